// Round 1
// baseline (421.593 us; speedup 1.0000x reference)
//
#include <hip/hip_runtime.h>
#include <cmath>

#define EPS 1e-5f
#define SZ 2097152  // N*H*W*E = 4*64*64*128

__device__ __forceinline__ float dot4(float4 a, float4 b) {
  return fmaf(a.x, b.x, fmaf(a.y, b.y, fmaf(a.z, b.z, a.w * b.w)));
}

// ---------------------------------------------------------------- K1: LN1 + transpose
// grid 256 = (n*64+y), block 256
__global__ __launch_bounds__(256) void k_ln1(const float* __restrict__ x,
    const float* __restrict__ g, const float* __restrict__ b,
    float* __restrict__ xnhwc, float* __restrict__ xn) {
  __shared__ float tile[128 * 65];
  __shared__ float mres[64], rres[64];
  int bid = blockIdx.x;
  int n = bid >> 6, y = bid & 63;
  const float* xb = x + (size_t)n * (128 * 64 * 64) + y * 64;
  int tid = threadIdx.x;
  for (int it = 0; it < 32; ++it) {
    int flat = it * 256 + tid;            // 8192 = 128c * 64x
    int c = flat >> 6, xp = flat & 63;
    tile[c * 65 + xp] = xb[(size_t)c * 4096 + xp];
  }
  __syncthreads();
  if (tid < 64) {
    float s = 0.f, sq = 0.f;
    for (int c = 0; c < 128; ++c) { float v = tile[c * 65 + tid]; s += v; sq += v * v; }
    float m = s * (1.f / 128.f);
    float var = sq * (1.f / 128.f) - m * m;
    mres[tid] = m;
    rres[tid] = rsqrtf(var + EPS);
  }
  __syncthreads();
  size_t rowbase = (size_t)bid * (64 * 128);
  for (int it = 0; it < 32; ++it) {
    int flat = it * 256 + tid;            // = px*128 + c
    int c = flat & 127, px = flat >> 7;
    float v = tile[c * 65 + px];
    xnhwc[rowbase + flat] = v;
    xn[rowbase + flat] = (v - mres[px]) * rres[px] * g[c] + b[c];
  }
}

// ---------------------------------------------------------------- K2: QKV projection
// grid 256 = (n*64+y), block 256
__global__ __launch_bounds__(256) void k_qkv(const float* __restrict__ xn,
    const float* __restrict__ wq, const float* __restrict__ bq,
    const float* __restrict__ wk, const float* __restrict__ bk,
    const float* __restrict__ wv, const float* __restrict__ bv,
    float* __restrict__ q, float* __restrict__ k, float* __restrict__ v) {
  __shared__ float xs[64 * 132];
  __shared__ float ws[128 * 132];
  int tid = threadIdx.x;
  size_t rowbase = (size_t)blockIdx.x * (64 * 128);
  for (int it = 0; it < 32; ++it) {
    int flat = it * 256 + tid;
    xs[(flat >> 7) * 132 + (flat & 127)] = xn[rowbase + flat];
  }
  int pg = tid & 15, og = tid >> 4;   // px = jp*16+pg, o = jo*16+og (stride-1 lanes: conflict-free)
  const float* wptr[3] = {wq, wk, wv};
  const float* bptr[3] = {bq, bk, bv};
  float* optr[3] = {q, k, v};
  for (int m = 0; m < 3; ++m) {
    __syncthreads();
    const float* w = wptr[m];
    for (int it = 0; it < 64; ++it) {
      int flat = it * 256 + tid;
      ws[(flat >> 7) * 132 + (flat & 127)] = w[flat];
    }
    __syncthreads();
    float acc[4][8];
#pragma unroll
    for (int jp = 0; jp < 4; ++jp)
#pragma unroll
      for (int jo = 0; jo < 8; ++jo) acc[jp][jo] = 0.f;
    for (int cc = 0; cc < 128; cc += 4) {
      float4 xv[4], wv4[8];
#pragma unroll
      for (int jp = 0; jp < 4; ++jp) xv[jp] = *(const float4*)&xs[(jp * 16 + pg) * 132 + cc];
#pragma unroll
      for (int jo = 0; jo < 8; ++jo) wv4[jo] = *(const float4*)&ws[(jo * 16 + og) * 132 + cc];
#pragma unroll
      for (int jp = 0; jp < 4; ++jp)
#pragma unroll
        for (int jo = 0; jo < 8; ++jo) acc[jp][jo] += dot4(xv[jp], wv4[jo]);
    }
    const float* bb = bptr[m];
    float* op = optr[m];
#pragma unroll
    for (int jp = 0; jp < 4; ++jp) {
      int px = jp * 16 + pg;
#pragma unroll
      for (int jo = 0; jo < 8; ++jo) {
        int o = jo * 16 + og;
        op[rowbase + px * 128 + o] = acc[jp][jo] + bb[o];
      }
    }
  }
}

// ---------------------------------------------------------------- K3: local-window attention
// grid 1024 = ((n*64+y)*4+h), block 256; thread = (px = tid>>2, sub = tid&3)
__global__ __launch_bounds__(256) void k_attn(const float* __restrict__ qb,
    const float* __restrict__ kb, const float* __restrict__ vb,
    const float* __restrict__ rel_bias, float* __restrict__ z0) {
  __shared__ float win[7 * 8 * 70 * 4];   // [dy][d4][xx] float4 (d in groups of 4)
  __shared__ float ss[64 * 50];           // scores / attn per pixel
  int bid = blockIdx.x;
  int h = bid & 3; int ny = bid >> 2; int y = ny & 63; int n = ny >> 6;
  int tid = threadIdx.x;
  int px = tid >> 2, sub = tid & 3;
  size_t base_nh = (size_t)n * (64 * 64 * 128) + h * 32;
  float4 qv[8];
  {
    const float* qp = qb + base_nh + (size_t)(y * 64 + px) * 128;
#pragma unroll
    for (int i = 0; i < 8; ++i) qv[i] = *(const float4*)&qp[i * 4];
  }
  // stage K window (zero-padded, matches reference: pad AFTER bias)
  for (int flat = tid; flat < 7 * 70 * 32; flat += 256) {
    int d = flat & 31;
    int rest = flat >> 5;
    int xx = rest % 70;
    int r = rest / 70;
    int yy = y - 3 + r;
    int gx = xx - 3;
    float val = 0.f;
    if (yy >= 0 && yy < 64 && gx >= 0 && gx < 64)
      val = kb[base_nh + (size_t)(yy * 64 + gx) * 128 + d];
    win[((r * 8 + (d >> 2)) * 70 + xx) * 4 + (d & 3)] = val;
  }
  __syncthreads();
  // scores for this thread's slice of the 49 positions
  {
    int p0 = sub * 12, pcnt = (sub == 3) ? 13 : 12;
    for (int pi = 0; pi < pcnt; ++pi) {
      int p = p0 + pi;
      int dy = p / 7, dx = p - dy * 7;
      int xx = px + dx;
      float s = 0.f;
#pragma unroll
      for (int d4 = 0; d4 < 8; ++d4) {
        float4 kv4 = *(const float4*)&win[((dy * 8 + d4) * 70 + xx) * 4];
        s += dot4(qv[d4], kv4);
      }
      ss[px * 50 + p] = s + rel_bias[h * 49 + p];
    }
  }
  __syncthreads();
  // stage V window (overwrites win) while sub==0 lanes run the softmax on ss
  for (int flat = tid; flat < 7 * 70 * 32; flat += 256) {
    int d = flat & 31;
    int rest = flat >> 5;
    int xx = rest % 70;
    int r = rest / 70;
    int yy = y - 3 + r;
    int gx = xx - 3;
    float val = 0.f;
    if (yy >= 0 && yy < 64 && gx >= 0 && gx < 64)
      val = vb[base_nh + (size_t)(yy * 64 + gx) * 128 + d];
    win[((r * 8 + (d >> 2)) * 70 + xx) * 4 + (d & 3)] = val;
  }
  if (sub == 0) {
    float mx = -1e30f;
    for (int p = 0; p < 49; ++p) mx = fmaxf(mx, ss[px * 50 + p]);
    float sum = 0.f;
    for (int p = 0; p < 49; ++p) {
      float e = __expf(ss[px * 50 + p] - mx);
      ss[px * 50 + p] = e;
      sum += e;
    }
    float inv = 1.f / sum;
    for (int p = 0; p < 49; ++p) ss[px * 50 + p] *= inv;
  }
  __syncthreads();
  // PV: this thread handles dims d = sub*8 .. sub*8+8
  float acc[8];
#pragma unroll
  for (int i = 0; i < 8; ++i) acc[i] = 0.f;
  for (int p = 0; p < 49; ++p) {
    int dy = p / 7, dx = p - dy * 7;
    int xx = px + dx;
    float a = ss[px * 50 + p];
    float4 v0 = *(const float4*)&win[((dy * 8 + sub * 2) * 70 + xx) * 4];
    float4 v1 = *(const float4*)&win[((dy * 8 + sub * 2 + 1) * 70 + xx) * 4];
    acc[0] = fmaf(a, v0.x, acc[0]); acc[1] = fmaf(a, v0.y, acc[1]);
    acc[2] = fmaf(a, v0.z, acc[2]); acc[3] = fmaf(a, v0.w, acc[3]);
    acc[4] = fmaf(a, v1.x, acc[4]); acc[5] = fmaf(a, v1.y, acc[5]);
    acc[6] = fmaf(a, v1.z, acc[6]); acc[7] = fmaf(a, v1.w, acc[7]);
  }
  float* zp = z0 + base_nh + (size_t)(y * 64 + px) * 128 + sub * 8;
  *(float4*)&zp[0] = make_float4(acc[0], acc[1], acc[2], acc[3]);
  *(float4*)&zp[4] = make_float4(acc[4], acc[5], acc[6], acc[7]);
}

// ---------------------------------------------------------------- K4: t = bil_w . qcoeff
// grid 64, block 256: thread handles one (o,i), 4 batches
__global__ __launch_bounds__(256) void k_t(const float* __restrict__ bil_w,
    const float* __restrict__ qcoeff, float* __restrict__ t) {
  __shared__ float qs[4 * 64];
  int tid = threadIdx.x;
  qs[tid] = qcoeff[tid];
  __syncthreads();
  int flat = blockIdx.x * 256 + tid;          // o*128 + i
  const float* wrow = bil_w + (size_t)flat * 64;
  float acc[4] = {0.f, 0.f, 0.f, 0.f};
  for (int qq = 0; qq < 64; qq += 4) {
    float4 w4 = *(const float4*)&wrow[qq];
#pragma unroll
    for (int nn = 0; nn < 4; ++nn) {
      const float* qc = &qs[nn * 64 + qq];
      acc[nn] = fmaf(w4.x, qc[0], fmaf(w4.y, qc[1], fmaf(w4.z, qc[2], fmaf(w4.w, qc[3], acc[nn]))));
    }
  }
#pragma unroll
  for (int nn = 0; nn < 4; ++nn) t[nn * 16384 + flat] = acc[nn];
}

// ---------------------------------------------------------------- K5: bilinear + residual + LN2
// grid 256 = (n*64+y), block 256
__global__ __launch_bounds__(256) void k_bil(const float* __restrict__ z0,
    const float* __restrict__ t, const float* __restrict__ bil_b,
    const float* __restrict__ xnhwc, const float* __restrict__ g2,
    const float* __restrict__ b2ln, float* __restrict__ z2,
    float* __restrict__ z3) {
  __shared__ float zs[64 * 132];
  __shared__ float ts[128 * 132];
  __shared__ float z2s[64 * 132];
  __shared__ float mres[64], rres[64];
  int tid = threadIdx.x;
  int bid = blockIdx.x;
  int n = bid >> 6;
  size_t rowbase = (size_t)bid * (64 * 128);
  for (int it = 0; it < 32; ++it) {
    int flat = it * 256 + tid;
    zs[(flat >> 7) * 132 + (flat & 127)] = z0[rowbase + flat];
  }
  const float* tn = t + (size_t)n * 16384;
  for (int it = 0; it < 64; ++it) {
    int flat = it * 256 + tid;
    ts[(flat >> 7) * 132 + (flat & 127)] = tn[flat];
  }
  __syncthreads();
  int pg = tid & 15, og = tid >> 4;
  float acc[4][8];
#pragma unroll
  for (int jp = 0; jp < 4; ++jp)
#pragma unroll
    for (int jo = 0; jo < 8; ++jo) acc[jp][jo] = 0.f;
  for (int cc = 0; cc < 128; cc += 4) {
    float4 zv[4], tv[8];
#pragma unroll
    for (int jp = 0; jp < 4; ++jp) zv[jp] = *(const float4*)&zs[(jp * 16 + pg) * 132 + cc];
#pragma unroll
    for (int jo = 0; jo < 8; ++jo) tv[jo] = *(const float4*)&ts[(jo * 16 + og) * 132 + cc];
#pragma unroll
    for (int jp = 0; jp < 4; ++jp)
#pragma unroll
      for (int jo = 0; jo < 8; ++jo) acc[jp][jo] += dot4(zv[jp], tv[jo]);
  }
#pragma unroll
  for (int jp = 0; jp < 4; ++jp) {
    int pxx = jp * 16 + pg;
    const float* xr = &xnhwc[rowbase + pxx * 128];
#pragma unroll
    for (int jo = 0; jo < 8; ++jo) {
      int o = jo * 16 + og;
      z2s[pxx * 132 + o] = acc[jp][jo] + bil_b[o] + xr[o];
    }
  }
  __syncthreads();
  if (tid < 64) {
    float s = 0.f, sq = 0.f;
    for (int c = 0; c < 128; ++c) { float vv = z2s[tid * 132 + c]; s += vv; sq += vv * vv; }
    float m = s * (1.f / 128.f);
    float var = sq * (1.f / 128.f) - m * m;
    mres[tid] = m;
    rres[tid] = rsqrtf(var + EPS);
  }
  __syncthreads();
  for (int it = 0; it < 32; ++it) {
    int flat = it * 256 + tid;
    int c = flat & 127, pxx = flat >> 7;
    float vv = z2s[pxx * 132 + c];
    z2[rowbase + flat] = vv;
    z3[rowbase + flat] = (vv - mres[pxx]) * rres[pxx] * g2[c] + b2ln[c];
  }
}

// ---------------------------------------------------------------- K6: FFN + residual + NCHW write
// grid 256 = (n*64+y), block 256; f-chunks of 64
__global__ __launch_bounds__(256) void k_ffn(const float* __restrict__ z3,
    const float* __restrict__ z2, const float* __restrict__ w1,
    const float* __restrict__ b1, const float* __restrict__ w2,
    const float* __restrict__ b2, float* __restrict__ out) {
  __shared__ float z3s[64 * 132];
  __shared__ float w1s[64 * 132];
  __shared__ float h1s[64 * 68];
  __shared__ float w2s[128 * 68];
  int tid = threadIdx.x;
  int bid = blockIdx.x;
  int n = bid >> 6, y = bid & 63;
  size_t rowbase = (size_t)bid * (64 * 128);
  for (int it = 0; it < 32; ++it) {
    int flat = it * 256 + tid;
    z3s[(flat >> 7) * 132 + (flat & 127)] = z3[rowbase + flat];
  }
  int pg = tid & 15, og = tid >> 4;   // phase3 / epilogue: px = jp*16+pg, o = jo*16+og
  float zacc[4][8];
#pragma unroll
  for (int jp = 0; jp < 4; ++jp)
#pragma unroll
    for (int jo = 0; jo < 8; ++jo) zacc[jp][jo] = b2[jo * 16 + og];
  for (int fc = 0; fc < 512; fc += 64) {
    __syncthreads();  // protect w1s/w2s/h1s from previous iteration's readers
    for (int it = 0; it < 32; ++it) {
      int flat = it * 256 + tid;
      int f = flat >> 7, c = flat & 127;
      w1s[f * 132 + c] = w1[(size_t)(fc + f) * 128 + c];
    }
    for (int it = 0; it < 32; ++it) {
      int flat = it * 256 + tid;
      int o = flat >> 6, j = flat & 63;
      w2s[o * 68 + j] = w2[(size_t)o * 512 + fc + j];
    }
    __syncthreads();
    // phase 2: h1 chunk, thread = (f = jf*16+fg, px = jp*16+pgq)
    int fg = pg, pgq = og;
    float hacc[4][4];
#pragma unroll
    for (int jf = 0; jf < 4; ++jf)
#pragma unroll
      for (int jp = 0; jp < 4; ++jp) hacc[jf][jp] = 0.f;
    for (int cc = 0; cc < 128; cc += 4) {
      float4 wv[4], zv[4];
#pragma unroll
      for (int jf = 0; jf < 4; ++jf) wv[jf] = *(const float4*)&w1s[(jf * 16 + fg) * 132 + cc];
#pragma unroll
      for (int jp = 0; jp < 4; ++jp) zv[jp] = *(const float4*)&z3s[(jp * 16 + pgq) * 132 + cc];
#pragma unroll
      for (int jf = 0; jf < 4; ++jf)
#pragma unroll
        for (int jp = 0; jp < 4; ++jp) hacc[jf][jp] += dot4(wv[jf], zv[jp]);
    }
#pragma unroll
    for (int jf = 0; jf < 4; ++jf) {
      int f = jf * 16 + fg;
      float bb1 = b1[fc + f];
#pragma unroll
      for (int jp = 0; jp < 4; ++jp) {
        int pxx = jp * 16 + pgq;
        float hv = hacc[jf][jp] + bb1;
        float ge = 0.5f * hv * (1.f + erff(hv * 0.70710678118f));  // exact GELU
        h1s[pxx * 68 + f] = ge;
      }
    }
    __syncthreads();
    // phase 3: z4 += h1_chunk @ w2_chunk^T
    for (int ff = 0; ff < 64; ff += 4) {
      float4 hv4[4], wv4[8];
#pragma unroll
      for (int jp = 0; jp < 4; ++jp) hv4[jp] = *(const float4*)&h1s[(jp * 16 + pg) * 68 + ff];
#pragma unroll
      for (int jo = 0; jo < 8; ++jo) wv4[jo] = *(const float4*)&w2s[(jo * 16 + og) * 68 + ff];
#pragma unroll
      for (int jp = 0; jp < 4; ++jp)
#pragma unroll
        for (int jo = 0; jo < 8; ++jo) zacc[jp][jo] += dot4(hv4[jp], wv4[jo]);
    }
  }
  // epilogue: + z2 residual, transposed NCHW store
#pragma unroll
  for (int jp = 0; jp < 4; ++jp) {
    int pxx = jp * 16 + pg;
    const float* zr = &z2[rowbase + pxx * 128];
#pragma unroll
    for (int jo = 0; jo < 8; ++jo) {
      int o = jo * 16 + og;
      out[((size_t)(n * 128 + o) * 64 + y) * 64 + pxx] = zacc[jp][jo] + zr[o];
    }
  }
}

// ----------------------------------------------------------------
extern "C" void kernel_launch(void* const* d_in, const int* in_sizes, int n_in,
                              void* d_out, int out_size, void* d_ws, size_t ws_size,
                              hipStream_t stream) {
  const float* x        = (const float*)d_in[0];
  const float* qcoeff   = (const float*)d_in[1];
  const float* wq       = (const float*)d_in[2];
  const float* bq       = (const float*)d_in[3];
  const float* wk       = (const float*)d_in[4];
  const float* bk       = (const float*)d_in[5];
  const float* wv       = (const float*)d_in[6];
  const float* bv       = (const float*)d_in[7];
  const float* rel_bias = (const float*)d_in[8];
  const float* ln1_g    = (const float*)d_in[9];
  const float* ln1_b    = (const float*)d_in[10];
  const float* bil_w    = (const float*)d_in[11];
  const float* bil_b    = (const float*)d_in[12];
  const float* ln2_g    = (const float*)d_in[13];
  const float* ln2_b    = (const float*)d_in[14];
  const float* w1       = (const float*)d_in[15];
  const float* b1       = (const float*)d_in[16];
  const float* w2       = (const float*)d_in[17];
  const float* b2       = (const float*)d_in[18];
  float* out = (float*)d_out;

  float* ws = (float*)d_ws;
  float* x_nhwc = ws;            // [N,H,W,E]
  float* xn     = ws + 1 * SZ;   // LN1 output; aliased as z0 after QKV
  float* qb     = ws + 2 * SZ;   // aliased as z2 after attention
  float* kb     = ws + 3 * SZ;   // aliased as z3 after attention
  float* vb     = ws + 4 * SZ;
  float* tb     = ws + 5 * SZ;   // [4,128,128]
  float* z0 = xn;
  float* z2 = qb;
  float* z3 = kb;

  k_ln1<<<256, 256, 0, stream>>>(x, ln1_g, ln1_b, x_nhwc, xn);
  k_qkv<<<256, 256, 0, stream>>>(xn, wq, bq, wk, bk, wv, bv, qb, kb, vb);
  k_t<<<64, 256, 0, stream>>>(bil_w, qcoeff, tb);
  k_attn<<<1024, 256, 0, stream>>>(qb, kb, vb, rel_bias, z0);
  k_bil<<<256, 256, 0, stream>>>(z0, tb, bil_b, x_nhwc, ln2_g, ln2_b, z2, z3);
  k_ffn<<<256, 256, 0, stream>>>(z3, z2, w1, b1, w2, b2, out);
}

// Round 2
// 275.637 us; speedup vs baseline: 1.5295x; 1.5295x over previous
//
#include <hip/hip_runtime.h>
#include <cmath>

#define EPS 1e-5f
#define SZ 2097152  // N*H*W*E = 4*64*64*128

typedef __attribute__((ext_vector_type(8))) short short8;   // 8 bf16 (4 VGPRs)
typedef __attribute__((ext_vector_type(4))) float floatx4;  // MFMA C/D frag

__device__ __forceinline__ float dot4(float4 a, float4 b) {
  return fmaf(a.x, b.x, fmaf(a.y, b.y, fmaf(a.z, b.z, a.w * b.w)));
}

__device__ __forceinline__ short f2bf(float f) {
  union { float f; unsigned u; } v; v.f = f;
  unsigned r = v.u + 0x7fff + ((v.u >> 16) & 1);  // RNE
  return (short)(r >> 16);
}

#define MFMA16(a, b, c) __builtin_amdgcn_mfma_f32_16x16x32_bf16(a, b, c, 0, 0, 0)

// ---------------------------------------------------------------- K1: LN1 + transpose
// grid 256 = (n*64+y), block 256
__global__ __launch_bounds__(256) void k_ln1(const float* __restrict__ x,
    const float* __restrict__ g, const float* __restrict__ b,
    float* __restrict__ xnhwc, float* __restrict__ xn) {
  __shared__ float tile[128 * 65];
  __shared__ float mres[64], rres[64];
  int bid = blockIdx.x;
  int n = bid >> 6, y = bid & 63;
  const float* xb = x + (size_t)n * (128 * 64 * 64) + y * 64;
  int tid = threadIdx.x;
  for (int it = 0; it < 32; ++it) {
    int flat = it * 256 + tid;            // 8192 = 128c * 64x
    int c = flat >> 6, xp = flat & 63;
    tile[c * 65 + xp] = xb[(size_t)c * 4096 + xp];
  }
  __syncthreads();
  if (tid < 64) {
    float s = 0.f, sq = 0.f;
    for (int c = 0; c < 128; ++c) { float v = tile[c * 65 + tid]; s += v; sq += v * v; }
    float m = s * (1.f / 128.f);
    float var = sq * (1.f / 128.f) - m * m;
    mres[tid] = m;
    rres[tid] = rsqrtf(var + EPS);
  }
  __syncthreads();
  size_t rowbase = (size_t)bid * (64 * 128);
  for (int it = 0; it < 32; ++it) {
    int flat = it * 256 + tid;            // = px*128 + c
    int c = flat & 127, px = flat >> 7;
    float v = tile[c * 65 + px];
    xnhwc[rowbase + flat] = v;
    xn[rowbase + flat] = (v - mres[px]) * rres[px] * g[c] + b[c];
  }
}

// ---------------------------------------------------------------- K2: QKV projection (MFMA bf16)
// grid 256 = (n*64+y), block 256 = 4 waves; wave = (wm = M-half, wn = N-half)
__global__ __launch_bounds__(256) void k_qkv(const float* __restrict__ xn,
    const float* __restrict__ wq, const float* __restrict__ bq,
    const float* __restrict__ wk, const float* __restrict__ bk,
    const float* __restrict__ wv, const float* __restrict__ bv,
    float* __restrict__ q, float* __restrict__ k, float* __restrict__ v) {
  __shared__ __align__(16) short xs[64 * 136];   // A: [px][c] bf16, pad 136
  __shared__ __align__(16) short ws[128 * 136];  // B: [o][c] bf16
  int tid = threadIdx.x;
  size_t rowbase = (size_t)blockIdx.x * (64 * 128);
  for (int it = 0; it < 8; ++it) {
    int flat = (it * 256 + tid) * 4;
    int px = flat >> 7, c = flat & 127;
    float4 xv = *(const float4*)&xn[rowbase + flat];
    short tmp[4] = {f2bf(xv.x), f2bf(xv.y), f2bf(xv.z), f2bf(xv.w)};
    *(uint2*)&xs[px * 136 + c] = *(uint2*)tmp;
  }
  __syncthreads();
  int w = tid >> 6, lane = tid & 63;
  int quad = lane >> 4, r16 = lane & 15;
  int wm = w & 1, wn = w >> 1;
  int px0 = wm * 32;
  short8 a[2][4];
#pragma unroll
  for (int mt = 0; mt < 2; ++mt)
#pragma unroll
    for (int kk = 0; kk < 4; ++kk)
      a[mt][kk] = *(const short8*)&xs[(px0 + mt * 16 + r16) * 136 + kk * 32 + quad * 8];
  const float* wptr[3] = {wq, wk, wv};
  const float* bptr[3] = {bq, bk, bv};
  float* optr[3] = {q, k, v};
  for (int m = 0; m < 3; ++m) {
    __syncthreads();
    const float* wp = wptr[m];
    for (int it = 0; it < 16; ++it) {
      int flat = (it * 256 + tid) * 4;
      int o = flat >> 7, c = flat & 127;
      float4 wv4 = *(const float4*)&wp[flat];
      short tmp[4] = {f2bf(wv4.x), f2bf(wv4.y), f2bf(wv4.z), f2bf(wv4.w)};
      *(uint2*)&ws[o * 136 + c] = *(uint2*)tmp;
    }
    __syncthreads();
    const float* bb = bptr[m];
    float* op = optr[m];
#pragma unroll
    for (int nt = 0; nt < 4; ++nt) {
      int o0 = wn * 64 + nt * 16;
      floatx4 acc0 = {0.f, 0.f, 0.f, 0.f}, acc1 = {0.f, 0.f, 0.f, 0.f};
#pragma unroll
      for (int kk = 0; kk < 4; ++kk) {
        short8 bfr = *(const short8*)&ws[(o0 + r16) * 136 + kk * 32 + quad * 8];
        acc0 = MFMA16(a[0][kk], bfr, acc0);
        acc1 = MFMA16(a[1][kk], bfr, acc1);
      }
      float bv2 = bb[o0 + r16];
#pragma unroll
      for (int r = 0; r < 4; ++r) {
        int px = px0 + quad * 4 + r;
        op[rowbase + px * 128 + o0 + r16] = acc0[r] + bv2;
        op[rowbase + (px + 16) * 128 + o0 + r16] = acc1[r] + bv2;
      }
    }
  }
}

// ---------------------------------------------------------------- K3: local-window attention (fp32)
// grid 1024 = ((n*64+y)*4+h), block 256; thread = (px = tid>>2, sub = tid&3)
__global__ __launch_bounds__(256) void k_attn(const float* __restrict__ qb,
    const float* __restrict__ kb, const float* __restrict__ vb,
    const float* __restrict__ rel_bias, float* __restrict__ z0) {
  __shared__ float win[7 * 8 * 70 * 4];   // [dy][d4][xx] float4 (d in groups of 4)
  __shared__ float ss[64 * 50];           // scores / attn per pixel
  int bid = blockIdx.x;
  int h = bid & 3; int ny = bid >> 2; int y = ny & 63; int n = ny >> 6;
  int tid = threadIdx.x;
  int px = tid >> 2, sub = tid & 3;
  size_t base_nh = (size_t)n * (64 * 64 * 128) + h * 32;
  float4 qv[8];
  {
    const float* qp = qb + base_nh + (size_t)(y * 64 + px) * 128;
#pragma unroll
    for (int i = 0; i < 8; ++i) qv[i] = *(const float4*)&qp[i * 4];
  }
  for (int flat = tid; flat < 7 * 70 * 32; flat += 256) {
    int d = flat & 31;
    int rest = flat >> 5;
    int xx = rest % 70;
    int r = rest / 70;
    int yy = y - 3 + r;
    int gx = xx - 3;
    float val = 0.f;
    if (yy >= 0 && yy < 64 && gx >= 0 && gx < 64)
      val = kb[base_nh + (size_t)(yy * 64 + gx) * 128 + d];
    win[((r * 8 + (d >> 2)) * 70 + xx) * 4 + (d & 3)] = val;
  }
  __syncthreads();
  {
    int p0 = sub * 12, pcnt = (sub == 3) ? 13 : 12;
    for (int pi = 0; pi < pcnt; ++pi) {
      int p = p0 + pi;
      int dy = p / 7, dx = p - dy * 7;
      int xx = px + dx;
      float s = 0.f;
#pragma unroll
      for (int d4 = 0; d4 < 8; ++d4) {
        float4 kv4 = *(const float4*)&win[((dy * 8 + d4) * 70 + xx) * 4];
        s += dot4(qv[d4], kv4);
      }
      ss[px * 50 + p] = s + rel_bias[h * 49 + p];
    }
  }
  __syncthreads();
  for (int flat = tid; flat < 7 * 70 * 32; flat += 256) {
    int d = flat & 31;
    int rest = flat >> 5;
    int xx = rest % 70;
    int r = rest / 70;
    int yy = y - 3 + r;
    int gx = xx - 3;
    float val = 0.f;
    if (yy >= 0 && yy < 64 && gx >= 0 && gx < 64)
      val = vb[base_nh + (size_t)(yy * 64 + gx) * 128 + d];
    win[((r * 8 + (d >> 2)) * 70 + xx) * 4 + (d & 3)] = val;
  }
  if (sub == 0) {
    float mx = -1e30f;
    for (int p = 0; p < 49; ++p) mx = fmaxf(mx, ss[px * 50 + p]);
    float sum = 0.f;
    for (int p = 0; p < 49; ++p) {
      float e = __expf(ss[px * 50 + p] - mx);
      ss[px * 50 + p] = e;
      sum += e;
    }
    float inv = 1.f / sum;
    for (int p = 0; p < 49; ++p) ss[px * 50 + p] *= inv;
  }
  __syncthreads();
  float acc[8];
#pragma unroll
  for (int i = 0; i < 8; ++i) acc[i] = 0.f;
  for (int p = 0; p < 49; ++p) {
    int dy = p / 7, dx = p - dy * 7;
    int xx = px + dx;
    float a = ss[px * 50 + p];
    float4 v0 = *(const float4*)&win[((dy * 8 + sub * 2) * 70 + xx) * 4];
    float4 v1 = *(const float4*)&win[((dy * 8 + sub * 2 + 1) * 70 + xx) * 4];
    acc[0] = fmaf(a, v0.x, acc[0]); acc[1] = fmaf(a, v0.y, acc[1]);
    acc[2] = fmaf(a, v0.z, acc[2]); acc[3] = fmaf(a, v0.w, acc[3]);
    acc[4] = fmaf(a, v1.x, acc[4]); acc[5] = fmaf(a, v1.y, acc[5]);
    acc[6] = fmaf(a, v1.z, acc[6]); acc[7] = fmaf(a, v1.w, acc[7]);
  }
  float* zp = z0 + base_nh + (size_t)(y * 64 + px) * 128 + sub * 8;
  *(float4*)&zp[0] = make_float4(acc[0], acc[1], acc[2], acc[3]);
  *(float4*)&zp[4] = make_float4(acc[4], acc[5], acc[6], acc[7]);
}

// ---------------------------------------------------------------- K4: t = bil_w . qcoeff -> bf16
// grid 64, block 256: thread handles one (o,i), 4 batches
__global__ __launch_bounds__(256) void k_t(const float* __restrict__ bil_w,
    const float* __restrict__ qcoeff, short* __restrict__ t) {
  __shared__ float qs[4 * 64];
  int tid = threadIdx.x;
  qs[tid] = qcoeff[tid];
  __syncthreads();
  int flat = blockIdx.x * 256 + tid;          // o*128 + i
  const float* wrow = bil_w + (size_t)flat * 64;
  float acc[4] = {0.f, 0.f, 0.f, 0.f};
  for (int qq = 0; qq < 64; qq += 4) {
    float4 w4 = *(const float4*)&wrow[qq];
#pragma unroll
    for (int nn = 0; nn < 4; ++nn) {
      const float* qc = &qs[nn * 64 + qq];
      acc[nn] = fmaf(w4.x, qc[0], fmaf(w4.y, qc[1], fmaf(w4.z, qc[2], fmaf(w4.w, qc[3], acc[nn]))));
    }
  }
#pragma unroll
  for (int nn = 0; nn < 4; ++nn) t[nn * 16384 + flat] = f2bf(acc[nn]);
}

// ---------------------------------------------------------------- K5: bilinear (MFMA) + residual + LN2
// grid 256 = (n*64+y), block 256
__global__ __launch_bounds__(256) void k_bil(const float* __restrict__ z0,
    const short* __restrict__ tb, const float* __restrict__ bil_b,
    const float* __restrict__ xnhwc, const float* __restrict__ g2,
    const float* __restrict__ b2ln, float* __restrict__ z2,
    float* __restrict__ z3) {
  __shared__ __align__(16) short zs[64 * 136];
  __shared__ __align__(16) short ts[128 * 136];
  __shared__ __align__(16) float z2s[64 * 132];
  __shared__ float mres[64], rres[64];
  int tid = threadIdx.x;
  int bid = blockIdx.x;
  int n = bid >> 6;
  size_t rowbase = (size_t)bid * (64 * 128);
  for (int it = 0; it < 8; ++it) {
    int flat = (it * 256 + tid) * 4;
    int px = flat >> 7, c = flat & 127;
    float4 v = *(const float4*)&z0[rowbase + flat];
    short tmp[4] = {f2bf(v.x), f2bf(v.y), f2bf(v.z), f2bf(v.w)};
    *(uint2*)&zs[px * 136 + c] = *(uint2*)tmp;
  }
  const short* tn = tb + (size_t)n * 16384;
  for (int it = 0; it < 8; ++it) {
    int flat = (it * 256 + tid) * 8;
    int o = flat >> 7, i = flat & 127;
    *(short8*)&ts[o * 136 + i] = *(const short8*)&tn[flat];
  }
  __syncthreads();
  int w = tid >> 6, lane = tid & 63;
  int quad = lane >> 4, r16 = lane & 15;
  int wm = w & 1, wn = w >> 1;
  int px0 = wm * 32;
  short8 a[2][4];
#pragma unroll
  for (int mt = 0; mt < 2; ++mt)
#pragma unroll
    for (int kk = 0; kk < 4; ++kk)
      a[mt][kk] = *(const short8*)&zs[(px0 + mt * 16 + r16) * 136 + kk * 32 + quad * 8];
#pragma unroll
  for (int nt = 0; nt < 4; ++nt) {
    int o0 = wn * 64 + nt * 16;
    floatx4 acc0 = {0.f, 0.f, 0.f, 0.f}, acc1 = {0.f, 0.f, 0.f, 0.f};
#pragma unroll
    for (int kk = 0; kk < 4; ++kk) {
      short8 bfr = *(const short8*)&ts[(o0 + r16) * 136 + kk * 32 + quad * 8];
      acc0 = MFMA16(a[0][kk], bfr, acc0);
      acc1 = MFMA16(a[1][kk], bfr, acc1);
    }
    float bb = bil_b[o0 + r16];
#pragma unroll
    for (int r = 0; r < 4; ++r) {
      int px = px0 + quad * 4 + r;
      z2s[px * 132 + o0 + r16] = acc0[r] + bb + xnhwc[rowbase + px * 128 + o0 + r16];
      z2s[(px + 16) * 132 + o0 + r16] =
          acc1[r] + bb + xnhwc[rowbase + (px + 16) * 128 + o0 + r16];
    }
  }
  __syncthreads();
  if (tid < 64) {
    float s = 0.f, sq = 0.f;
    for (int c = 0; c < 128; ++c) { float vv = z2s[tid * 132 + c]; s += vv; sq += vv * vv; }
    float m = s * (1.f / 128.f);
    float var = sq * (1.f / 128.f) - m * m;
    mres[tid] = m;
    rres[tid] = rsqrtf(var + EPS);
  }
  __syncthreads();
  for (int it = 0; it < 32; ++it) {
    int flat = it * 256 + tid;
    int c = flat & 127, pxx = flat >> 7;
    float vv = z2s[pxx * 132 + c];
    z2[rowbase + flat] = vv;
    z3[rowbase + flat] = (vv - mres[pxx]) * rres[pxx] * g2[c] + b2ln[c];
  }
}

// ---------------------------------------------------------------- K6: FFN (MFMA) + residual + NCHW
// grid 256 = (n*64+y), block 256 = 4 waves; f-chunks of 128
__global__ __launch_bounds__(256) void k_ffn(const float* __restrict__ z3,
    const float* __restrict__ z2, const float* __restrict__ w1,
    const float* __restrict__ b1, const float* __restrict__ w2,
    const float* __restrict__ b2, float* __restrict__ out) {
  __shared__ __align__(16) char smem[17408 + 34816 + 17408 + 34816];
  short* z3s = (short*)smem;                          // [64px][136c] bf16
  short* w1c = (short*)(smem + 17408);                // [128f][136c] bf16
  short* h1s = (short*)(smem + 17408 + 34816);        // [64px][136f] bf16
  short* w2c = (short*)(smem + 17408 + 34816 + 17408);// [128o][136f] bf16
  float* outt = (float*)(smem + 17408);               // [128o][65px] fp32 (aliases w1c)
  int tid = threadIdx.x;
  int bid = blockIdx.x;
  int n = bid >> 6, y = bid & 63;
  size_t rowbase = (size_t)bid * (64 * 128);
  for (int it = 0; it < 8; ++it) {
    int flat = (it * 256 + tid) * 4;
    int px = flat >> 7, c = flat & 127;
    float4 v = *(const float4*)&z3[rowbase + flat];
    short tmp[4] = {f2bf(v.x), f2bf(v.y), f2bf(v.z), f2bf(v.w)};
    *(uint2*)&z3s[px * 136 + c] = *(uint2*)tmp;
  }
  __syncthreads();
  int w = tid >> 6, lane = tid & 63;
  int quad = lane >> 4, r16 = lane & 15;
  int wm = w & 1, wn = w >> 1;
  int px0 = wm * 32;
  short8 a3[2][4];
#pragma unroll
  for (int mt = 0; mt < 2; ++mt)
#pragma unroll
    for (int kk = 0; kk < 4; ++kk)
      a3[mt][kk] = *(const short8*)&z3s[(px0 + mt * 16 + r16) * 136 + kk * 32 + quad * 8];
  floatx4 zacc[2][4];
#pragma unroll
  for (int mt = 0; mt < 2; ++mt)
#pragma unroll
    for (int nt = 0; nt < 4; ++nt) zacc[mt][nt] = (floatx4){0.f, 0.f, 0.f, 0.f};
  for (int fc = 0; fc < 512; fc += 128) {
    __syncthreads();  // protect w1c/w2c/h1s from previous iteration readers
    for (int it = 0; it < 16; ++it) {
      int flat = (it * 256 + tid) * 4;
      int f = flat >> 7, c = flat & 127;
      float4 v = *(const float4*)&w1[(size_t)(fc + f) * 128 + c];
      short tmp[4] = {f2bf(v.x), f2bf(v.y), f2bf(v.z), f2bf(v.w)};
      *(uint2*)&w1c[f * 136 + c] = *(uint2*)tmp;
    }
    for (int it = 0; it < 16; ++it) {
      int flat = (it * 256 + tid) * 4;
      int o = flat >> 7, j = flat & 127;
      float4 v = *(const float4*)&w2[(size_t)o * 512 + fc + j];
      short tmp[4] = {f2bf(v.x), f2bf(v.y), f2bf(v.z), f2bf(v.w)};
      *(uint2*)&w2c[o * 136 + j] = *(uint2*)tmp;
    }
    __syncthreads();
    // GEMM1: h1 chunk [64px][128f] = z3 @ w1c^T, + bias, GELU, -> h1s bf16
#pragma unroll
    for (int nt = 0; nt < 4; ++nt) {
      int f0 = wn * 64 + nt * 16;
      floatx4 acc0 = {0.f, 0.f, 0.f, 0.f}, acc1 = {0.f, 0.f, 0.f, 0.f};
#pragma unroll
      for (int kk = 0; kk < 4; ++kk) {
        short8 bfr = *(const short8*)&w1c[(f0 + r16) * 136 + kk * 32 + quad * 8];
        acc0 = MFMA16(a3[0][kk], bfr, acc0);
        acc1 = MFMA16(a3[1][kk], bfr, acc1);
      }
      float bb1 = b1[fc + f0 + r16];
#pragma unroll
      for (int r = 0; r < 4; ++r) {
        float hv = acc0[r] + bb1;
        float ge = 0.5f * hv * (1.f + erff(hv * 0.70710678118f));
        h1s[(px0 + quad * 4 + r) * 136 + f0 + r16] = f2bf(ge);
        float hv2 = acc1[r] + bb1;
        float ge2 = 0.5f * hv2 * (1.f + erff(hv2 * 0.70710678118f));
        h1s[(px0 + 16 + quad * 4 + r) * 136 + f0 + r16] = f2bf(ge2);
      }
    }
    __syncthreads();
    // GEMM2 partial: zacc += h1s @ w2c^T (K = 128 local f)
    short8 ah[2][4];
#pragma unroll
    for (int mt = 0; mt < 2; ++mt)
#pragma unroll
      for (int kk = 0; kk < 4; ++kk)
        ah[mt][kk] = *(const short8*)&h1s[(px0 + mt * 16 + r16) * 136 + kk * 32 + quad * 8];
#pragma unroll
    for (int nt = 0; nt < 4; ++nt) {
      int o0 = wn * 64 + nt * 16;
#pragma unroll
      for (int kk = 0; kk < 4; ++kk) {
        short8 bfr = *(const short8*)&w2c[(o0 + r16) * 136 + kk * 32 + quad * 8];
        zacc[0][nt] = MFMA16(ah[0][kk], bfr, zacc[0][nt]);
        zacc[1][nt] = MFMA16(ah[1][kk], bfr, zacc[1][nt]);
      }
    }
  }
  __syncthreads();  // done with w1c -> outt alias safe
  // epilogue: + b2 + z2 residual, transpose via LDS, coalesced NCHW store
#pragma unroll
  for (int nt = 0; nt < 4; ++nt) {
    int o0 = wn * 64 + nt * 16;
    float bb = b2[o0 + r16];
#pragma unroll
    for (int mt = 0; mt < 2; ++mt)
#pragma unroll
      for (int r = 0; r < 4; ++r) {
        int px = px0 + mt * 16 + quad * 4 + r;
        outt[(o0 + r16) * 65 + px] =
            zacc[mt][nt][r] + bb + z2[rowbase + px * 128 + o0 + r16];
      }
  }
  __syncthreads();
  for (int it = 0; it < 32; ++it) {
    int flat = it * 256 + tid;   // o*64 + px
    int o = flat >> 6, px = flat & 63;
    out[(((size_t)(n * 128 + o)) * 64 + y) * 64 + px] = outt[o * 65 + px];
  }
}

// ----------------------------------------------------------------
extern "C" void kernel_launch(void* const* d_in, const int* in_sizes, int n_in,
                              void* d_out, int out_size, void* d_ws, size_t ws_size,
                              hipStream_t stream) {
  const float* x        = (const float*)d_in[0];
  const float* qcoeff   = (const float*)d_in[1];
  const float* wq       = (const float*)d_in[2];
  const float* bq       = (const float*)d_in[3];
  const float* wk       = (const float*)d_in[4];
  const float* bk       = (const float*)d_in[5];
  const float* wv       = (const float*)d_in[6];
  const float* bv       = (const float*)d_in[7];
  const float* rel_bias = (const float*)d_in[8];
  const float* ln1_g    = (const float*)d_in[9];
  const float* ln1_b    = (const float*)d_in[10];
  const float* bil_w    = (const float*)d_in[11];
  const float* bil_b    = (const float*)d_in[12];
  const float* ln2_g    = (const float*)d_in[13];
  const float* ln2_b    = (const float*)d_in[14];
  const float* w1       = (const float*)d_in[15];
  const float* b1       = (const float*)d_in[16];
  const float* w2       = (const float*)d_in[17];
  const float* b2       = (const float*)d_in[18];
  float* out = (float*)d_out;

  float* ws = (float*)d_ws;
  float* x_nhwc = ws;            // [N,H,W,E]
  float* xn     = ws + 1 * SZ;   // LN1 output; aliased as z0 after QKV
  float* qb     = ws + 2 * SZ;   // aliased as z2 after attention
  float* kb     = ws + 3 * SZ;   // aliased as z3 after attention
  float* vb     = ws + 4 * SZ;
  short* tb     = (short*)(ws + 5 * SZ);   // [4,128,128] bf16
  float* z0 = xn;
  float* z2 = qb;
  float* z3 = kb;

  k_ln1<<<256, 256, 0, stream>>>(x, ln1_g, ln1_b, x_nhwc, xn);
  k_qkv<<<256, 256, 0, stream>>>(xn, wq, bq, wk, bk, wv, bv, qb, kb, vb);
  k_t<<<64, 256, 0, stream>>>(bil_w, qcoeff, tb);
  k_attn<<<1024, 256, 0, stream>>>(qb, kb, vb, rel_bias, z0);
  k_bil<<<256, 256, 0, stream>>>(z0, tb, bil_b, x_nhwc, ln2_g, ln2_b, z2, z3);
  k_ffn<<<256, 256, 0, stream>>>(z3, z2, w1, b1, w2, b2, out);
}

// Round 3
// 238.816 us; speedup vs baseline: 1.7653x; 1.1542x over previous
//
#include <hip/hip_runtime.h>
#include <cmath>

#define EPS 1e-5f
#define SZ 2097152  // N*H*W*E = 4*64*64*128

typedef __attribute__((ext_vector_type(8))) short short8;   // 8 bf16 (4 VGPRs)
typedef __attribute__((ext_vector_type(4))) float floatx4;  // MFMA C/D frag

__device__ __forceinline__ float dot4(float4 a, float4 b) {
  return fmaf(a.x, b.x, fmaf(a.y, b.y, fmaf(a.z, b.z, a.w * b.w)));
}

__device__ __forceinline__ short f2bf(float f) {
  union { float f; unsigned u; } v; v.f = f;
  unsigned r = v.u + 0x7fff + ((v.u >> 16) & 1);  // RNE
  return (short)(r >> 16);
}

#define MFMA16(a, b, c) __builtin_amdgcn_mfma_f32_16x16x32_bf16(a, b, c, 0, 0, 0)

// ---------------------------------------------------------------- K1: LN1 + transpose
// grid 256 = (n*64+y), block 256
__global__ __launch_bounds__(256) void k_ln1(const float* __restrict__ x,
    const float* __restrict__ g, const float* __restrict__ b,
    float* __restrict__ xnhwc, float* __restrict__ xn) {
  __shared__ float tile[128 * 65];
  __shared__ float mres[64], rres[64];
  int bid = blockIdx.x;
  int n = bid >> 6, y = bid & 63;
  const float* xb = x + (size_t)n * (128 * 64 * 64) + y * 64;
  int tid = threadIdx.x;
  for (int it = 0; it < 32; ++it) {
    int flat = it * 256 + tid;            // 8192 = 128c * 64x
    int c = flat >> 6, xp = flat & 63;
    tile[c * 65 + xp] = xb[(size_t)c * 4096 + xp];
  }
  __syncthreads();
  if (tid < 64) {
    float s = 0.f, sq = 0.f;
    for (int c = 0; c < 128; ++c) { float v = tile[c * 65 + tid]; s += v; sq += v * v; }
    float m = s * (1.f / 128.f);
    float var = sq * (1.f / 128.f) - m * m;
    mres[tid] = m;
    rres[tid] = rsqrtf(var + EPS);
  }
  __syncthreads();
  size_t rowbase = (size_t)bid * (64 * 128);
  for (int it = 0; it < 32; ++it) {
    int flat = it * 256 + tid;            // = px*128 + c
    int c = flat & 127, px = flat >> 7;
    float v = tile[c * 65 + px];
    xnhwc[rowbase + flat] = v;
    xn[rowbase + flat] = (v - mres[px]) * rres[px] * g[c] + b[c];
  }
}

// ---------------------------------------------------------------- K2: QKV projection (MFMA bf16)
// grid 256 = (n*64+y), block 256 = 4 waves; wave = (wm = M-half, wn = N-half)
__global__ __launch_bounds__(256) void k_qkv(const float* __restrict__ xn,
    const float* __restrict__ wq, const float* __restrict__ bq,
    const float* __restrict__ wk, const float* __restrict__ bk,
    const float* __restrict__ wv, const float* __restrict__ bv,
    float* __restrict__ q, float* __restrict__ k, float* __restrict__ v) {
  __shared__ __align__(16) short xs[64 * 136];   // A: [px][c] bf16, pad 136
  __shared__ __align__(16) short ws[128 * 136];  // B: [o][c] bf16
  int tid = threadIdx.x;
  size_t rowbase = (size_t)blockIdx.x * (64 * 128);
  for (int it = 0; it < 8; ++it) {
    int flat = (it * 256 + tid) * 4;
    int px = flat >> 7, c = flat & 127;
    float4 xv = *(const float4*)&xn[rowbase + flat];
    short tmp[4] = {f2bf(xv.x), f2bf(xv.y), f2bf(xv.z), f2bf(xv.w)};
    *(uint2*)&xs[px * 136 + c] = *(uint2*)tmp;
  }
  __syncthreads();
  int w = tid >> 6, lane = tid & 63;
  int quad = lane >> 4, r16 = lane & 15;
  int wm = w & 1, wn = w >> 1;
  int px0 = wm * 32;
  short8 a[2][4];
#pragma unroll
  for (int mt = 0; mt < 2; ++mt)
#pragma unroll
    for (int kk = 0; kk < 4; ++kk)
      a[mt][kk] = *(const short8*)&xs[(px0 + mt * 16 + r16) * 136 + kk * 32 + quad * 8];
  const float* wptr[3] = {wq, wk, wv};
  const float* bptr[3] = {bq, bk, bv};
  float* optr[3] = {q, k, v};
  for (int m = 0; m < 3; ++m) {
    __syncthreads();
    const float* wp = wptr[m];
    for (int it = 0; it < 16; ++it) {
      int flat = (it * 256 + tid) * 4;
      int o = flat >> 7, c = flat & 127;
      float4 wv4 = *(const float4*)&wp[flat];
      short tmp[4] = {f2bf(wv4.x), f2bf(wv4.y), f2bf(wv4.z), f2bf(wv4.w)};
      *(uint2*)&ws[o * 136 + c] = *(uint2*)tmp;
    }
    __syncthreads();
    const float* bb = bptr[m];
    float* op = optr[m];
#pragma unroll
    for (int nt = 0; nt < 4; ++nt) {
      int o0 = wn * 64 + nt * 16;
      floatx4 acc0 = {0.f, 0.f, 0.f, 0.f}, acc1 = {0.f, 0.f, 0.f, 0.f};
#pragma unroll
      for (int kk = 0; kk < 4; ++kk) {
        short8 bfr = *(const short8*)&ws[(o0 + r16) * 136 + kk * 32 + quad * 8];
        acc0 = MFMA16(a[0][kk], bfr, acc0);
        acc1 = MFMA16(a[1][kk], bfr, acc1);
      }
      float bv2 = bb[o0 + r16];
#pragma unroll
      for (int r = 0; r < 4; ++r) {
        int px = px0 + quad * 4 + r;
        op[rowbase + px * 128 + o0 + r16] = acc0[r] + bv2;
        op[rowbase + (px + 16) * 128 + o0 + r16] = acc1[r] + bv2;
      }
    }
  }
}

// ---------------------------------------------------------------- K3: local-window attention (MFMA, banded)
// grid 1024 = ((n*64+y)*4+h), block 256 = 4 waves; wave w owns px strip [16w,16w+16)
__global__ __launch_bounds__(256) void k_attn(const float* __restrict__ qb,
    const float* __restrict__ kb, const float* __restrict__ vb,
    const float* __restrict__ rel_bias, float* __restrict__ z0) {
  // LDS plan (union: Ks then Vt in same region):
  //  Qs  [64][40] bf16         5120 B
  //  KV  Ks [7][80][40] bf16 (44800) / Vt [7][32][104] bf16 (46592)
  //  ssf [64][52] f32          13312 B   scores -> attn
  //  Ab  [64][104] bf16        13312 B   banded attn A-matrix (zeroed once)
  //  bias[49] f32              256 B
  __shared__ __align__(16) char smem[5120 + 46592 + 13312 + 13312 + 256];
  short* Qs = (short*)smem;
  short* KV = (short*)(smem + 5120);
  float* ssf = (float*)(smem + 5120 + 46592);
  short* Ab = (short*)(smem + 5120 + 46592 + 13312);
  float* bias = (float*)(smem + 5120 + 46592 + 13312 + 13312);

  int bid = blockIdx.x;
  int h = bid & 3, y = (bid >> 2) & 63, n = bid >> 8;
  int tid = threadIdx.x;
  size_t base_nh = (size_t)n * (64 * 64 * 128) + h * 32;
  const float* qrow = qb + base_nh + (size_t)y * 64 * 128;

  // stage Q -> bf16 [64][40]
  for (int it = 0; it < 2; ++it) {
    int i = it * 256 + tid;               // 512 = 64px * 8d4
    int px = i >> 3, d4 = i & 7;
    float4 v = *(const float4*)&qrow[px * 128 + d4 * 4];
    short t4[4] = {f2bf(v.x), f2bf(v.y), f2bf(v.z), f2bf(v.w)};
    *(uint2*)&Qs[px * 40 + d4 * 4] = *(uint2*)t4;
  }
  // stage K window rows -> Ks[r][xx][d], zero outside image (matches reference pad)
  for (int r = 0; r < 7; ++r) {
    int yy = y + r - 3;
    for (int i = tid; i < 560; i += 256) {  // 70xx * 8d4
      int xx = i >> 3, d4 = i & 7;
      int gx = xx - 3;
      float4 v = make_float4(0.f, 0.f, 0.f, 0.f);
      if (yy >= 0 && yy < 64 && gx >= 0 && gx < 64)
        v = *(const float4*)&kb[base_nh + (size_t)(yy * 64 + gx) * 128 + d4 * 4];
      short t4[4] = {f2bf(v.x), f2bf(v.y), f2bf(v.z), f2bf(v.w)};
      *(uint2*)&KV[(r * 80 + xx) * 40 + d4 * 4] = *(uint2*)t4;
    }
  }
  if (tid < 49) bias[tid] = rel_bias[h * 49 + tid];
  __syncthreads();

  int w = tid >> 6, lane = tid & 63;
  int quad = lane >> 4, r16 = lane & 15;
  int strip = w * 16;
  // QK^T: only the 2 N-tiles intersecting the band of this strip
  short8 qf = *(const short8*)&Qs[(strip + r16) * 40 + quad * 8];
#pragma unroll
  for (int r = 0; r < 7; ++r) {
#pragma unroll
    for (int t = 0; t < 2; ++t) {
      int xxc = (w + t) * 16 + r16;
      short8 bf = *(const short8*)&KV[(r * 80 + xxc) * 40 + quad * 8];
      floatx4 c = MFMA16(qf, bf, ((floatx4){0.f, 0.f, 0.f, 0.f}));
#pragma unroll
      for (int rr = 0; rr < 4; ++rr) {
        int px = strip + quad * 4 + rr;
        int dx = xxc - px;
        if ((unsigned)dx < 7u) ssf[px * 52 + r * 7 + dx] = c[rr] + bias[r * 7 + dx];
      }
    }
  }
  __syncthreads();
  // stage V^T -> Vt[r][d][xx] (overwrites Ks), zero pad xx in [70,96); zero Ab; softmax
  for (int r = 0; r < 7; ++r) {
    int yy = y + r - 3;
    for (int i = tid; i < 560; i += 256) {
      int xx = i >> 3, d4 = i & 7;
      int gx = xx - 3;
      float4 v = make_float4(0.f, 0.f, 0.f, 0.f);
      if (yy >= 0 && yy < 64 && gx >= 0 && gx < 64)
        v = *(const float4*)&vb[base_nh + (size_t)(yy * 64 + gx) * 128 + d4 * 4];
      KV[(r * 32 + d4 * 4 + 0) * 104 + xx] = f2bf(v.x);
      KV[(r * 32 + d4 * 4 + 1) * 104 + xx] = f2bf(v.y);
      KV[(r * 32 + d4 * 4 + 2) * 104 + xx] = f2bf(v.z);
      KV[(r * 32 + d4 * 4 + 3) * 104 + xx] = f2bf(v.w);
    }
  }
  {
    unsigned* kvd = (unsigned*)KV;           // rows are 52 dwords; zero dwords 35..47 (xx 70..95)
    for (int i = tid; i < 7 * 32 * 13; i += 256) {
      int row = i / 13, xd = i - row * 13;
      kvd[row * 52 + 35 + xd] = 0u;
    }
    unsigned* ad = (unsigned*)Ab;
    for (int i = tid; i < 3328; i += 256) ad[i] = 0u;
  }
  {
    int px = tid >> 2, sub = tid & 3;
    int p0 = sub * 12, cnt = (sub == 3) ? 13 : 12;
    float sv[13];
    float mx = -1e30f;
    for (int pi = 0; pi < cnt; ++pi) { sv[pi] = ssf[px * 52 + p0 + pi]; mx = fmaxf(mx, sv[pi]); }
    mx = fmaxf(mx, __shfl_xor(mx, 1));
    mx = fmaxf(mx, __shfl_xor(mx, 2));
    float sum = 0.f;
    for (int pi = 0; pi < cnt; ++pi) { float e = __expf(sv[pi] - mx); sv[pi] = e; sum += e; }
    sum += __shfl_xor(sum, 1);
    sum += __shfl_xor(sum, 2);
    float inv = 1.f / sum;
    for (int pi = 0; pi < cnt; ++pi) ssf[px * 52 + p0 + pi] = sv[pi] * inv;
  }
  __syncthreads();
  // PV: per r scatter banded attn into Ab (band slots identical across r), then MFMA
  floatx4 oacc[2] = {(floatx4){0.f, 0.f, 0.f, 0.f}, (floatx4){0.f, 0.f, 0.f, 0.f}};
  int px_s = tid >> 2, sub = tid & 3;
  int k0 = strip >> 5, k1 = (strip + 22) >> 5;
  for (int r = 0; r < 7; ++r) {
    Ab[px_s * 104 + px_s + sub] = f2bf(ssf[px_s * 52 + r * 7 + sub]);
    if (sub < 3)
      Ab[px_s * 104 + px_s + sub + 4] = f2bf(ssf[px_s * 52 + r * 7 + sub + 4]);
    __syncthreads();
    for (int kk = k0; kk <= k1; ++kk) {
      short8 af = *(const short8*)&Ab[(strip + r16) * 104 + kk * 32 + quad * 8];
#pragma unroll
      for (int nt = 0; nt < 2; ++nt) {
        short8 vf = *(const short8*)&KV[(r * 32 + nt * 16 + r16) * 104 + kk * 32 + quad * 8];
        oacc[nt] = MFMA16(af, vf, oacc[nt]);
      }
    }
    __syncthreads();
  }
  // epilogue: C[px][d] -> z0
  float* zrow = z0 + base_nh + (size_t)y * 64 * 128;
#pragma unroll
  for (int nt = 0; nt < 2; ++nt)
#pragma unroll
    for (int rr = 0; rr < 4; ++rr) {
      int px = strip + quad * 4 + rr;
      zrow[px * 128 + nt * 16 + r16] = oacc[nt][rr];
    }
}

// ---------------------------------------------------------------- K4: t = bil_w . qcoeff -> bf16
// grid 64, block 256: thread handles one (o,i), 4 batches
__global__ __launch_bounds__(256) void k_t(const float* __restrict__ bil_w,
    const float* __restrict__ qcoeff, short* __restrict__ t) {
  __shared__ float qs[4 * 64];
  int tid = threadIdx.x;
  qs[tid] = qcoeff[tid];
  __syncthreads();
  int flat = blockIdx.x * 256 + tid;          // o*128 + i
  const float* wrow = bil_w + (size_t)flat * 64;
  float acc[4] = {0.f, 0.f, 0.f, 0.f};
  for (int qq = 0; qq < 64; qq += 4) {
    float4 w4 = *(const float4*)&wrow[qq];
#pragma unroll
    for (int nn = 0; nn < 4; ++nn) {
      const float* qc = &qs[nn * 64 + qq];
      acc[nn] = fmaf(w4.x, qc[0], fmaf(w4.y, qc[1], fmaf(w4.z, qc[2], fmaf(w4.w, qc[3], acc[nn]))));
    }
  }
#pragma unroll
  for (int nn = 0; nn < 4; ++nn) t[nn * 16384 + flat] = f2bf(acc[nn]);
}

// ---------------------------------------------------------------- K5: bilinear (MFMA) + residual + LN2
// grid 256 = (n*64+y), block 256
__global__ __launch_bounds__(256) void k_bil(const float* __restrict__ z0,
    const short* __restrict__ tb, const float* __restrict__ bil_b,
    const float* __restrict__ xnhwc, const float* __restrict__ g2,
    const float* __restrict__ b2ln, float* __restrict__ z2,
    float* __restrict__ z3) {
  __shared__ __align__(16) short zs[64 * 136];
  __shared__ __align__(16) short ts[128 * 136];
  __shared__ __align__(16) float z2s[64 * 132];
  __shared__ float mres[64], rres[64];
  int tid = threadIdx.x;
  int bid = blockIdx.x;
  int n = bid >> 6;
  size_t rowbase = (size_t)bid * (64 * 128);
  for (int it = 0; it < 8; ++it) {
    int flat = (it * 256 + tid) * 4;
    int px = flat >> 7, c = flat & 127;
    float4 v = *(const float4*)&z0[rowbase + flat];
    short tmp[4] = {f2bf(v.x), f2bf(v.y), f2bf(v.z), f2bf(v.w)};
    *(uint2*)&zs[px * 136 + c] = *(uint2*)tmp;
  }
  const short* tn = tb + (size_t)n * 16384;
  for (int it = 0; it < 8; ++it) {
    int flat = (it * 256 + tid) * 8;
    int o = flat >> 7, i = flat & 127;
    *(short8*)&ts[o * 136 + i] = *(const short8*)&tn[flat];
  }
  __syncthreads();
  int w = tid >> 6, lane = tid & 63;
  int quad = lane >> 4, r16 = lane & 15;
  int wm = w & 1, wn = w >> 1;
  int px0 = wm * 32;
  short8 a[2][4];
#pragma unroll
  for (int mt = 0; mt < 2; ++mt)
#pragma unroll
    for (int kk = 0; kk < 4; ++kk)
      a[mt][kk] = *(const short8*)&zs[(px0 + mt * 16 + r16) * 136 + kk * 32 + quad * 8];
#pragma unroll
  for (int nt = 0; nt < 4; ++nt) {
    int o0 = wn * 64 + nt * 16;
    floatx4 acc0 = {0.f, 0.f, 0.f, 0.f}, acc1 = {0.f, 0.f, 0.f, 0.f};
#pragma unroll
    for (int kk = 0; kk < 4; ++kk) {
      short8 bfr = *(const short8*)&ts[(o0 + r16) * 136 + kk * 32 + quad * 8];
      acc0 = MFMA16(a[0][kk], bfr, acc0);
      acc1 = MFMA16(a[1][kk], bfr, acc1);
    }
    float bb = bil_b[o0 + r16];
#pragma unroll
    for (int r = 0; r < 4; ++r) {
      int px = px0 + quad * 4 + r;
      z2s[px * 132 + o0 + r16] = acc0[r] + bb + xnhwc[rowbase + px * 128 + o0 + r16];
      z2s[(px + 16) * 132 + o0 + r16] =
          acc1[r] + bb + xnhwc[rowbase + (px + 16) * 128 + o0 + r16];
    }
  }
  __syncthreads();
  if (tid < 64) {
    float s = 0.f, sq = 0.f;
    for (int c = 0; c < 128; ++c) { float vv = z2s[tid * 132 + c]; s += vv; sq += vv * vv; }
    float m = s * (1.f / 128.f);
    float var = sq * (1.f / 128.f) - m * m;
    mres[tid] = m;
    rres[tid] = rsqrtf(var + EPS);
  }
  __syncthreads();
  for (int it = 0; it < 32; ++it) {
    int flat = it * 256 + tid;
    int c = flat & 127, pxx = flat >> 7;
    float vv = z2s[pxx * 132 + c];
    z2[rowbase + flat] = vv;
    z3[rowbase + flat] = (vv - mres[pxx]) * rres[pxx] * g2[c] + b2ln[c];
  }
}

// ---------------------------------------------------------------- K6: FFN (MFMA) + residual + NCHW
// grid 256 = (n*64+y), block 256 = 4 waves; f-chunks of 128
__global__ __launch_bounds__(256) void k_ffn(const float* __restrict__ z3,
    const float* __restrict__ z2, const float* __restrict__ w1,
    const float* __restrict__ b1, const float* __restrict__ w2,
    const float* __restrict__ b2, float* __restrict__ out) {
  __shared__ __align__(16) char smem[17408 + 34816 + 17408 + 34816];
  short* z3s = (short*)smem;                          // [64px][136c] bf16
  short* w1c = (short*)(smem + 17408);                // [128f][136c] bf16
  short* h1s = (short*)(smem + 17408 + 34816);        // [64px][136f] bf16
  short* w2c = (short*)(smem + 17408 + 34816 + 17408);// [128o][136f] bf16
  float* outt = (float*)(smem + 17408);               // [128o][65px] fp32 (aliases w1c)
  int tid = threadIdx.x;
  int bid = blockIdx.x;
  int n = bid >> 6, y = bid & 63;
  size_t rowbase = (size_t)bid * (64 * 128);
  for (int it = 0; it < 8; ++it) {
    int flat = (it * 256 + tid) * 4;
    int px = flat >> 7, c = flat & 127;
    float4 v = *(const float4*)&z3[rowbase + flat];
    short tmp[4] = {f2bf(v.x), f2bf(v.y), f2bf(v.z), f2bf(v.w)};
    *(uint2*)&z3s[px * 136 + c] = *(uint2*)tmp;
  }
  __syncthreads();
  int w = tid >> 6, lane = tid & 63;
  int quad = lane >> 4, r16 = lane & 15;
  int wm = w & 1, wn = w >> 1;
  int px0 = wm * 32;
  short8 a3[2][4];
#pragma unroll
  for (int mt = 0; mt < 2; ++mt)
#pragma unroll
    for (int kk = 0; kk < 4; ++kk)
      a3[mt][kk] = *(const short8*)&z3s[(px0 + mt * 16 + r16) * 136 + kk * 32 + quad * 8];
  floatx4 zacc[2][4];
#pragma unroll
  for (int mt = 0; mt < 2; ++mt)
#pragma unroll
    for (int nt = 0; nt < 4; ++nt) zacc[mt][nt] = (floatx4){0.f, 0.f, 0.f, 0.f};
  for (int fc = 0; fc < 512; fc += 128) {
    __syncthreads();  // protect w1c/w2c/h1s from previous iteration readers
    for (int it = 0; it < 16; ++it) {
      int flat = (it * 256 + tid) * 4;
      int f = flat >> 7, c = flat & 127;
      float4 v = *(const float4*)&w1[(size_t)(fc + f) * 128 + c];
      short tmp[4] = {f2bf(v.x), f2bf(v.y), f2bf(v.z), f2bf(v.w)};
      *(uint2*)&w1c[f * 136 + c] = *(uint2*)tmp;
    }
    for (int it = 0; it < 16; ++it) {
      int flat = (it * 256 + tid) * 4;
      int o = flat >> 7, j = flat & 127;
      float4 v = *(const float4*)&w2[(size_t)o * 512 + fc + j];
      short tmp[4] = {f2bf(v.x), f2bf(v.y), f2bf(v.z), f2bf(v.w)};
      *(uint2*)&w2c[o * 136 + j] = *(uint2*)tmp;
    }
    __syncthreads();
    // GEMM1: h1 chunk [64px][128f] = z3 @ w1c^T, + bias, GELU, -> h1s bf16
#pragma unroll
    for (int nt = 0; nt < 4; ++nt) {
      int f0 = wn * 64 + nt * 16;
      floatx4 acc0 = {0.f, 0.f, 0.f, 0.f}, acc1 = {0.f, 0.f, 0.f, 0.f};
#pragma unroll
      for (int kk = 0; kk < 4; ++kk) {
        short8 bfr = *(const short8*)&w1c[(f0 + r16) * 136 + kk * 32 + quad * 8];
        acc0 = MFMA16(a3[0][kk], bfr, acc0);
        acc1 = MFMA16(a3[1][kk], bfr, acc1);
      }
      float bb1 = b1[fc + f0 + r16];
#pragma unroll
      for (int r = 0; r < 4; ++r) {
        float hv = acc0[r] + bb1;
        float ge = 0.5f * hv * (1.f + erff(hv * 0.70710678118f));
        h1s[(px0 + quad * 4 + r) * 136 + f0 + r16] = f2bf(ge);
        float hv2 = acc1[r] + bb1;
        float ge2 = 0.5f * hv2 * (1.f + erff(hv2 * 0.70710678118f));
        h1s[(px0 + 16 + quad * 4 + r) * 136 + f0 + r16] = f2bf(ge2);
      }
    }
    __syncthreads();
    // GEMM2 partial: zacc += h1s @ w2c^T (K = 128 local f)
    short8 ah[2][4];
#pragma unroll
    for (int mt = 0; mt < 2; ++mt)
#pragma unroll
      for (int kk = 0; kk < 4; ++kk)
        ah[mt][kk] = *(const short8*)&h1s[(px0 + mt * 16 + r16) * 136 + kk * 32 + quad * 8];
#pragma unroll
    for (int nt = 0; nt < 4; ++nt) {
      int o0 = wn * 64 + nt * 16;
#pragma unroll
      for (int kk = 0; kk < 4; ++kk) {
        short8 bfr = *(const short8*)&w2c[(o0 + r16) * 136 + kk * 32 + quad * 8];
        zacc[0][nt] = MFMA16(ah[0][kk], bfr, zacc[0][nt]);
        zacc[1][nt] = MFMA16(ah[1][kk], bfr, zacc[1][nt]);
      }
    }
  }
  __syncthreads();  // done with w1c -> outt alias safe
  // epilogue: + b2 + z2 residual, transpose via LDS, coalesced NCHW store
#pragma unroll
  for (int nt = 0; nt < 4; ++nt) {
    int o0 = wn * 64 + nt * 16;
    float bb = b2[o0 + r16];
#pragma unroll
    for (int mt = 0; mt < 2; ++mt)
#pragma unroll
      for (int r = 0; r < 4; ++r) {
        int px = px0 + mt * 16 + quad * 4 + r;
        outt[(o0 + r16) * 65 + px] =
            zacc[mt][nt][r] + bb + z2[rowbase + px * 128 + o0 + r16];
      }
  }
  __syncthreads();
  for (int it = 0; it < 32; ++it) {
    int flat = it * 256 + tid;   // o*64 + px
    int o = flat >> 6, px = flat & 63;
    out[(((size_t)(n * 128 + o)) * 64 + y) * 64 + px] = outt[o * 65 + px];
  }
}

// ----------------------------------------------------------------
extern "C" void kernel_launch(void* const* d_in, const int* in_sizes, int n_in,
                              void* d_out, int out_size, void* d_ws, size_t ws_size,
                              hipStream_t stream) {
  const float* x        = (const float*)d_in[0];
  const float* qcoeff   = (const float*)d_in[1];
  const float* wq       = (const float*)d_in[2];
  const float* bq       = (const float*)d_in[3];
  const float* wk       = (const float*)d_in[4];
  const float* bk       = (const float*)d_in[5];
  const float* wv       = (const float*)d_in[6];
  const float* bv       = (const float*)d_in[7];
  const float* rel_bias = (const float*)d_in[8];
  const float* ln1_g    = (const float*)d_in[9];
  const float* ln1_b    = (const float*)d_in[10];
  const float* bil_w    = (const float*)d_in[11];
  const float* bil_b    = (const float*)d_in[12];
  const float* ln2_g    = (const float*)d_in[13];
  const float* ln2_b    = (const float*)d_in[14];
  const float* w1       = (const float*)d_in[15];
  const float* b1       = (const float*)d_in[16];
  const float* w2       = (const float*)d_in[17];
  const float* b2       = (const float*)d_in[18];
  float* out = (float*)d_out;

  float* ws = (float*)d_ws;
  float* x_nhwc = ws;            // [N,H,W,E]
  float* xn     = ws + 1 * SZ;   // LN1 output; aliased as z0 after QKV
  float* qb     = ws + 2 * SZ;   // aliased as z2 after attention
  float* kb     = ws + 3 * SZ;   // aliased as z3 after attention
  float* vb     = ws + 4 * SZ;
  short* tb     = (short*)(ws + 5 * SZ);   // [4,128,128] bf16
  float* z0 = xn;
  float* z2 = qb;
  float* z3 = kb;

  k_ln1<<<256, 256, 0, stream>>>(x, ln1_g, ln1_b, x_nhwc, xn);
  k_qkv<<<256, 256, 0, stream>>>(xn, wq, bq, wk, bk, wv, bv, qb, kb, vb);
  k_t<<<64, 256, 0, stream>>>(bil_w, qcoeff, tb);
  k_attn<<<1024, 256, 0, stream>>>(qb, kb, vb, rel_bias, z0);
  k_bil<<<256, 256, 0, stream>>>(z0, tb, bil_b, x_nhwc, ln2_g, ln2_b, z2, z3);
  k_ffn<<<256, 256, 0, stream>>>(z3, z2, w1, b1, w2, b2, out);
}

// Round 4
// 191.971 us; speedup vs baseline: 2.1961x; 1.2440x over previous
//
#include <hip/hip_runtime.h>
#include <cmath>

#define EPS 1e-5f
#define SZ 2097152  // N*H*W*E = 4*64*64*128

typedef __attribute__((ext_vector_type(8))) short short8;   // 8 bf16 (4 VGPRs)
typedef __attribute__((ext_vector_type(4))) float floatx4;  // MFMA C/D frag

__device__ __forceinline__ float dot4(float4 a, float4 b) {
  return fmaf(a.x, b.x, fmaf(a.y, b.y, fmaf(a.z, b.z, a.w * b.w)));
}

__device__ __forceinline__ short f2bf(float f) {
  union { float f; unsigned u; } v; v.f = f;
  unsigned r = v.u + 0x7fff + ((v.u >> 16) & 1);  // RNE
  return (short)(r >> 16);
}

#define MFMA16(a, b, c) __builtin_amdgcn_mfma_f32_16x16x32_bf16(a, b, c, 0, 0, 0)

// ---------------------------------------------------------------- K0: weight prep (fp32 -> bf16, padded 136 rows)
// grid 64, block 256
__global__ __launch_bounds__(256) void k_prep(const float* __restrict__ w1,
    const float* __restrict__ w2, const float* __restrict__ wq,
    const float* __restrict__ wk, const float* __restrict__ wv,
    short* __restrict__ w1bf, short* __restrict__ w2bf,
    short* __restrict__ wqbf, short* __restrict__ wkbf, short* __restrict__ wvbf) {
  int tid0 = blockIdx.x * 256 + threadIdx.x;
  int stride = gridDim.x * 256;
  // w1 [512f][128c] -> [512][136]
  for (int i = tid0; i < 16384; i += stride) {
    int flat = i * 4; int f = flat >> 7, c = flat & 127;
    float4 v = *(const float4*)&w1[flat];
    short t4[4] = {f2bf(v.x), f2bf(v.y), f2bf(v.z), f2bf(v.w)};
    *(uint2*)&w1bf[f * 136 + c] = *(uint2*)t4;
  }
  // w2 [128o][512j] -> 4 chunks of [128o][136]
  for (int i = tid0; i < 16384; i += stride) {
    int flat = i * 4; int o = flat >> 9, j = flat & 511;
    int ck = j >> 7, jj = j & 127;
    float4 v = *(const float4*)&w2[flat];
    short t4[4] = {f2bf(v.x), f2bf(v.y), f2bf(v.z), f2bf(v.w)};
    *(uint2*)&w2bf[(ck * 128 + o) * 136 + jj] = *(uint2*)t4;
  }
  // wq/wk/wv [128o][128c] -> [128][136]
  for (int i = tid0; i < 4096; i += stride) {
    int flat = i * 4; int o = flat >> 7, c = flat & 127;
    float4 a = *(const float4*)&wq[flat];
    float4 b = *(const float4*)&wk[flat];
    float4 cc = *(const float4*)&wv[flat];
    short ta[4] = {f2bf(a.x), f2bf(a.y), f2bf(a.z), f2bf(a.w)};
    short tb4[4] = {f2bf(b.x), f2bf(b.y), f2bf(b.z), f2bf(b.w)};
    short tc[4] = {f2bf(cc.x), f2bf(cc.y), f2bf(cc.z), f2bf(cc.w)};
    *(uint2*)&wqbf[o * 136 + c] = *(uint2*)ta;
    *(uint2*)&wkbf[o * 136 + c] = *(uint2*)tb4;
    *(uint2*)&wvbf[o * 136 + c] = *(uint2*)tc;
  }
}

// ---------------------------------------------------------------- K1: LN1 + transpose
// grid 256 = (n*64+y), block 256
__global__ __launch_bounds__(256) void k_ln1(const float* __restrict__ x,
    const float* __restrict__ g, const float* __restrict__ b,
    float* __restrict__ xnhwc, float* __restrict__ xn) {
  __shared__ float tile[128 * 65];
  __shared__ float mres[64], rres[64];
  int bid = blockIdx.x;
  int n = bid >> 6, y = bid & 63;
  const float* xb = x + (size_t)n * (128 * 64 * 64) + y * 64;
  int tid = threadIdx.x;
  for (int it = 0; it < 32; ++it) {
    int flat = it * 256 + tid;            // 8192 = 128c * 64x
    int c = flat >> 6, xp = flat & 63;
    tile[c * 65 + xp] = xb[(size_t)c * 4096 + xp];
  }
  __syncthreads();
  if (tid < 64) {
    float s = 0.f, sq = 0.f;
    for (int c = 0; c < 128; ++c) { float v = tile[c * 65 + tid]; s += v; sq += v * v; }
    float m = s * (1.f / 128.f);
    float var = sq * (1.f / 128.f) - m * m;
    mres[tid] = m;
    rres[tid] = rsqrtf(var + EPS);
  }
  __syncthreads();
  size_t rowbase = (size_t)bid * (64 * 128);
  for (int it = 0; it < 32; ++it) {
    int flat = it * 256 + tid;            // = px*128 + c
    int c = flat & 127, px = flat >> 7;
    float v = tile[c * 65 + px];
    xnhwc[rowbase + flat] = v;
    xn[rowbase + flat] = (v - mres[px]) * rres[px] * g[c] + b[c];
  }
}

// ---------------------------------------------------------------- K2: QKV projection (MFMA bf16)
// grid 256 = (n*64+y), block 1024 = 16 waves; wave = (wm = 16-px strip, wn = 32-wide o quarter)
__global__ __launch_bounds__(1024) void k_qkv(const float* __restrict__ xn,
    const short* __restrict__ wqbf, const short* __restrict__ wkbf,
    const short* __restrict__ wvbf, const float* __restrict__ bq,
    const float* __restrict__ bk, const float* __restrict__ bv,
    float* __restrict__ q, float* __restrict__ k, float* __restrict__ v) {
  __shared__ __align__(16) short xs[64 * 136];   // A: [px][c]
  __shared__ __align__(16) short ws[128 * 136];  // B: [o][c]
  int tid = threadIdx.x;
  size_t rowbase = (size_t)blockIdx.x * (64 * 128);
  for (int it = 0; it < 2; ++it) {
    int flat = (it * 1024 + tid) * 4;
    int px = flat >> 7, c = flat & 127;
    float4 xv = *(const float4*)&xn[rowbase + flat];
    short tmp[4] = {f2bf(xv.x), f2bf(xv.y), f2bf(xv.z), f2bf(xv.w)};
    *(uint2*)&xs[px * 136 + c] = *(uint2*)tmp;
  }
  __syncthreads();
  int w = tid >> 6, lane = tid & 63;
  int quad = lane >> 4, r16 = lane & 15;
  int wm = w & 3, wn = w >> 2;
  int strip = wm * 16;
  short8 a[4];
#pragma unroll
  for (int kk = 0; kk < 4; ++kk)
    a[kk] = *(const short8*)&xs[(strip + r16) * 136 + kk * 32 + quad * 8];
  const short* wptr[3] = {wqbf, wkbf, wvbf};
  const float* bptr[3] = {bq, bk, bv};
  float* optr[3] = {q, k, v};
  for (int m = 0; m < 3; ++m) {
    __syncthreads();   // previous matrix's B-frag readers done
    const short* wp = wptr[m];
    for (int i = tid; i < 2176; i += 1024)
      *(short8*)&ws[i * 8] = *(const short8*)&wp[i * 8];
    __syncthreads();
    const float* bb = bptr[m];
    float* op = optr[m];
#pragma unroll
    for (int nt = 0; nt < 2; ++nt) {
      int o0 = wn * 32 + nt * 16;
      floatx4 acc = {0.f, 0.f, 0.f, 0.f};
#pragma unroll
      for (int kk = 0; kk < 4; ++kk) {
        short8 bfr = *(const short8*)&ws[(o0 + r16) * 136 + kk * 32 + quad * 8];
        acc = MFMA16(a[kk], bfr, acc);
      }
      float bv2 = bb[o0 + r16];
#pragma unroll
      for (int r = 0; r < 4; ++r) {
        int px = strip + quad * 4 + r;
        op[rowbase + px * 128 + o0 + r16] = acc[r] + bv2;
      }
    }
  }
}

// ---------------------------------------------------------------- K3: local-window attention (MFMA, banded)
// grid 1024 = ((n*64+y)*4+h), block 256 = 4 waves; wave w owns px strip [16w,16w+16)
__global__ __launch_bounds__(256) void k_attn(const float* __restrict__ qb,
    const float* __restrict__ kb, const float* __restrict__ vb,
    const float* __restrict__ rel_bias, float* __restrict__ z0) {
  __shared__ __align__(16) char smem[5120 + 46592 + 13312 + 13312 + 256];
  short* Qs = (short*)smem;
  short* KV = (short*)(smem + 5120);
  float* ssf = (float*)(smem + 5120 + 46592);
  short* Ab = (short*)(smem + 5120 + 46592 + 13312);
  float* bias = (float*)(smem + 5120 + 46592 + 13312 + 13312);

  int bid = blockIdx.x;
  int h = bid & 3, y = (bid >> 2) & 63, n = bid >> 8;
  int tid = threadIdx.x;
  size_t base_nh = (size_t)n * (64 * 64 * 128) + h * 32;
  const float* qrow = qb + base_nh + (size_t)y * 64 * 128;

  for (int it = 0; it < 2; ++it) {
    int i = it * 256 + tid;               // 512 = 64px * 8d4
    int px = i >> 3, d4 = i & 7;
    float4 v = *(const float4*)&qrow[px * 128 + d4 * 4];
    short t4[4] = {f2bf(v.x), f2bf(v.y), f2bf(v.z), f2bf(v.w)};
    *(uint2*)&Qs[px * 40 + d4 * 4] = *(uint2*)t4;
  }
  for (int r = 0; r < 7; ++r) {
    int yy = y + r - 3;
    for (int i = tid; i < 560; i += 256) {  // 70xx * 8d4
      int xx = i >> 3, d4 = i & 7;
      int gx = xx - 3;
      float4 v = make_float4(0.f, 0.f, 0.f, 0.f);
      if (yy >= 0 && yy < 64 && gx >= 0 && gx < 64)
        v = *(const float4*)&kb[base_nh + (size_t)(yy * 64 + gx) * 128 + d4 * 4];
      short t4[4] = {f2bf(v.x), f2bf(v.y), f2bf(v.z), f2bf(v.w)};
      *(uint2*)&KV[(r * 80 + xx) * 40 + d4 * 4] = *(uint2*)t4;
    }
  }
  if (tid < 49) bias[tid] = rel_bias[h * 49 + tid];
  __syncthreads();

  int w = tid >> 6, lane = tid & 63;
  int quad = lane >> 4, r16 = lane & 15;
  int strip = w * 16;
  short8 qf = *(const short8*)&Qs[(strip + r16) * 40 + quad * 8];
#pragma unroll
  for (int r = 0; r < 7; ++r) {
#pragma unroll
    for (int t = 0; t < 2; ++t) {
      int xxc = (w + t) * 16 + r16;
      short8 bf = *(const short8*)&KV[(r * 80 + xxc) * 40 + quad * 8];
      floatx4 c = MFMA16(qf, bf, ((floatx4){0.f, 0.f, 0.f, 0.f}));
#pragma unroll
      for (int rr = 0; rr < 4; ++rr) {
        int px = strip + quad * 4 + rr;
        int dx = xxc - px;
        if ((unsigned)dx < 7u) ssf[px * 52 + r * 7 + dx] = c[rr] + bias[r * 7 + dx];
      }
    }
  }
  __syncthreads();
  for (int r = 0; r < 7; ++r) {
    int yy = y + r - 3;
    for (int i = tid; i < 560; i += 256) {
      int xx = i >> 3, d4 = i & 7;
      int gx = xx - 3;
      float4 v = make_float4(0.f, 0.f, 0.f, 0.f);
      if (yy >= 0 && yy < 64 && gx >= 0 && gx < 64)
        v = *(const float4*)&vb[base_nh + (size_t)(yy * 64 + gx) * 128 + d4 * 4];
      KV[(r * 32 + d4 * 4 + 0) * 104 + xx] = f2bf(v.x);
      KV[(r * 32 + d4 * 4 + 1) * 104 + xx] = f2bf(v.y);
      KV[(r * 32 + d4 * 4 + 2) * 104 + xx] = f2bf(v.z);
      KV[(r * 32 + d4 * 4 + 3) * 104 + xx] = f2bf(v.w);
    }
  }
  {
    unsigned* kvd = (unsigned*)KV;
    for (int i = tid; i < 7 * 32 * 13; i += 256) {
      int row = i / 13, xd = i - row * 13;
      kvd[row * 52 + 35 + xd] = 0u;
    }
    unsigned* ad = (unsigned*)Ab;
    for (int i = tid; i < 3328; i += 256) ad[i] = 0u;
  }
  {
    int px = tid >> 2, sub = tid & 3;
    int p0 = sub * 12, cnt = (sub == 3) ? 13 : 12;
    float sv[13];
    float mx = -1e30f;
    for (int pi = 0; pi < cnt; ++pi) { sv[pi] = ssf[px * 52 + p0 + pi]; mx = fmaxf(mx, sv[pi]); }
    mx = fmaxf(mx, __shfl_xor(mx, 1));
    mx = fmaxf(mx, __shfl_xor(mx, 2));
    float sum = 0.f;
    for (int pi = 0; pi < cnt; ++pi) { float e = __expf(sv[pi] - mx); sv[pi] = e; sum += e; }
    sum += __shfl_xor(sum, 1);
    sum += __shfl_xor(sum, 2);
    float inv = 1.f / sum;
    for (int pi = 0; pi < cnt; ++pi) ssf[px * 52 + p0 + pi] = sv[pi] * inv;
  }
  __syncthreads();
  floatx4 oacc[2] = {(floatx4){0.f, 0.f, 0.f, 0.f}, (floatx4){0.f, 0.f, 0.f, 0.f}};
  int px_s = tid >> 2, sub = tid & 3;
  int k0 = strip >> 5, k1 = (strip + 22) >> 5;
  for (int r = 0; r < 7; ++r) {
    Ab[px_s * 104 + px_s + sub] = f2bf(ssf[px_s * 52 + r * 7 + sub]);
    if (sub < 3)
      Ab[px_s * 104 + px_s + sub + 4] = f2bf(ssf[px_s * 52 + r * 7 + sub + 4]);
    __syncthreads();
    for (int kk = k0; kk <= k1; ++kk) {
      short8 af = *(const short8*)&Ab[(strip + r16) * 104 + kk * 32 + quad * 8];
#pragma unroll
      for (int nt = 0; nt < 2; ++nt) {
        short8 vf = *(const short8*)&KV[(r * 32 + nt * 16 + r16) * 104 + kk * 32 + quad * 8];
        oacc[nt] = MFMA16(af, vf, oacc[nt]);
      }
    }
    __syncthreads();
  }
  float* zrow = z0 + base_nh + (size_t)y * 64 * 128;
#pragma unroll
  for (int nt = 0; nt < 2; ++nt)
#pragma unroll
    for (int rr = 0; rr < 4; ++rr) {
      int px = strip + quad * 4 + rr;
      zrow[px * 128 + nt * 16 + r16] = oacc[nt][rr];
    }
}

// ---------------------------------------------------------------- K4: t = bil_w . qcoeff -> bf16 (padded 136)
// grid 64, block 256
__global__ __launch_bounds__(256) void k_t(const float* __restrict__ bil_w,
    const float* __restrict__ qcoeff, short* __restrict__ t) {
  __shared__ float qs[4 * 64];
  int tid = threadIdx.x;
  qs[tid] = qcoeff[tid];
  __syncthreads();
  int flat = blockIdx.x * 256 + tid;          // o*128 + i
  const float* wrow = bil_w + (size_t)flat * 64;
  float acc[4] = {0.f, 0.f, 0.f, 0.f};
  for (int qq = 0; qq < 64; qq += 4) {
    float4 w4 = *(const float4*)&wrow[qq];
#pragma unroll
    for (int nn = 0; nn < 4; ++nn) {
      const float* qc = &qs[nn * 64 + qq];
      acc[nn] = fmaf(w4.x, qc[0], fmaf(w4.y, qc[1], fmaf(w4.z, qc[2], fmaf(w4.w, qc[3], acc[nn]))));
    }
  }
  int o = flat >> 7, i = flat & 127;
#pragma unroll
  for (int nn = 0; nn < 4; ++nn) t[nn * 17408 + o * 136 + i] = f2bf(acc[nn]);
}

// ---------------------------------------------------------------- K5: bilinear (MFMA) + residual + LN2
// grid 256 = (n*64+y), block 1024 = 16 waves
__global__ __launch_bounds__(1024) void k_bil(const float* __restrict__ z0,
    const short* __restrict__ tb, const float* __restrict__ bil_b,
    const float* __restrict__ xnhwc, const float* __restrict__ g2,
    const float* __restrict__ b2ln, float* __restrict__ z2,
    float* __restrict__ z3) {
  __shared__ __align__(16) short zs[64 * 136];
  __shared__ __align__(16) short ts[128 * 136];
  __shared__ __align__(16) float z2s[64 * 132];
  int tid = threadIdx.x;
  int bid = blockIdx.x;
  int n = bid >> 6;
  size_t rowbase = (size_t)bid * (64 * 128);
  for (int it = 0; it < 2; ++it) {
    int flat = (it * 1024 + tid) * 4;
    int px = flat >> 7, c = flat & 127;
    float4 v = *(const float4*)&z0[rowbase + flat];
    short tmp[4] = {f2bf(v.x), f2bf(v.y), f2bf(v.z), f2bf(v.w)};
    *(uint2*)&zs[px * 136 + c] = *(uint2*)tmp;
  }
  const short* tn = tb + (size_t)n * 17408;
  for (int i = tid; i < 2176; i += 1024)
    *(short8*)&ts[i * 8] = *(const short8*)&tn[i * 8];
  __syncthreads();
  int w = tid >> 6, lane = tid & 63;
  int quad = lane >> 4, r16 = lane & 15;
  int wm = w & 3, wn = w >> 2;
  int strip = wm * 16;
  short8 a[4];
#pragma unroll
  for (int kk = 0; kk < 4; ++kk)
    a[kk] = *(const short8*)&zs[(strip + r16) * 136 + kk * 32 + quad * 8];
#pragma unroll
  for (int nt = 0; nt < 2; ++nt) {
    int o0 = wn * 32 + nt * 16;
    floatx4 acc = {0.f, 0.f, 0.f, 0.f};
#pragma unroll
    for (int kk = 0; kk < 4; ++kk) {
      short8 bfr = *(const short8*)&ts[(o0 + r16) * 136 + kk * 32 + quad * 8];
      acc = MFMA16(a[kk], bfr, acc);
    }
    float bb = bil_b[o0 + r16];
#pragma unroll
    for (int r = 0; r < 4; ++r) {
      int px = strip + quad * 4 + r;
      z2s[px * 132 + o0 + r16] = acc[r] + bb + xnhwc[rowbase + px * 128 + o0 + r16];
    }
  }
  __syncthreads();
  // LN2: 16 lanes per px
  {
    int px = tid >> 4, cl = tid & 15;
    float4 v0 = *(const float4*)&z2s[px * 132 + cl * 8];
    float4 v1 = *(const float4*)&z2s[px * 132 + cl * 8 + 4];
    float s = v0.x + v0.y + v0.z + v0.w + v1.x + v1.y + v1.z + v1.w;
    float sq = dot4(v0, v0) + dot4(v1, v1);
    s += __shfl_xor(s, 1);  sq += __shfl_xor(sq, 1);
    s += __shfl_xor(s, 2);  sq += __shfl_xor(sq, 2);
    s += __shfl_xor(s, 4);  sq += __shfl_xor(sq, 4);
    s += __shfl_xor(s, 8);  sq += __shfl_xor(sq, 8);
    float m = s * (1.f / 128.f);
    float var = sq * (1.f / 128.f) - m * m;
    float rr = rsqrtf(var + EPS);
    int c0 = cl * 8;
    float o0v[8];
#pragma unroll
    for (int j = 0; j < 8; ++j) {
      float vv = (j < 4) ? (&v0.x)[j] : (&v1.x)[j - 4];
      o0v[j] = vv;
    }
    float* z2p = &z2[rowbase + px * 128 + c0];
    float* z3p = &z3[rowbase + px * 128 + c0];
#pragma unroll
    for (int j = 0; j < 8; ++j) {
      z2p[j] = o0v[j];
      z3p[j] = (o0v[j] - m) * rr * g2[c0 + j] + b2ln[c0 + j];
    }
  }
}

// ---------------------------------------------------------------- K6: FFN (MFMA) + residual + NCHW
// grid 256 = (n*64+y), block 1024 = 16 waves; f-chunks of 128
__global__ __launch_bounds__(1024) void k_ffn(const float* __restrict__ z3,
    const float* __restrict__ z2, const short* __restrict__ w1bf,
    const float* __restrict__ b1, const short* __restrict__ w2bf,
    const float* __restrict__ b2, float* __restrict__ out) {
  __shared__ __align__(16) char smem[17408 + 34816 + 17408 + 34816];
  short* z3s = (short*)smem;                          // [64px][136c]
  short* w1c = (short*)(smem + 17408);                // [128f][136c]
  short* h1s = (short*)(smem + 17408 + 34816);        // [64px][136f]
  short* w2c = (short*)(smem + 17408 + 34816 + 17408);// [128o][136j]
  float* outt = (float*)(smem + 17408);               // [128o][65px] fp32 (aliases w1c)
  int tid = threadIdx.x;
  int bid = blockIdx.x;
  int n = bid >> 6, y = bid & 63;
  size_t rowbase = (size_t)bid * (64 * 128);
  for (int it = 0; it < 2; ++it) {
    int flat = (it * 1024 + tid) * 4;
    int px = flat >> 7, c = flat & 127;
    float4 v = *(const float4*)&z3[rowbase + flat];
    short tmp[4] = {f2bf(v.x), f2bf(v.y), f2bf(v.z), f2bf(v.w)};
    *(uint2*)&z3s[px * 136 + c] = *(uint2*)tmp;
  }
  __syncthreads();
  int w = tid >> 6, lane = tid & 63;
  int quad = lane >> 4, r16 = lane & 15;
  int wm = w & 3, wn = w >> 2;
  int strip = wm * 16;
  short8 a3[4];
#pragma unroll
  for (int kk = 0; kk < 4; ++kk)
    a3[kk] = *(const short8*)&z3s[(strip + r16) * 136 + kk * 32 + quad * 8];
  floatx4 zacc[2];
  zacc[0] = (floatx4){0.f, 0.f, 0.f, 0.f};
  zacc[1] = (floatx4){0.f, 0.f, 0.f, 0.f};
  for (int fc = 0; fc < 512; fc += 128) {
    __syncthreads();  // protect w1c/w2c/h1s from previous iteration readers
    const short* w1src = w1bf + fc * 136;
    const short* w2src = w2bf + (fc >> 7) * 17408;
    for (int i = tid; i < 2176; i += 1024) {
      *(short8*)&w1c[i * 8] = *(const short8*)&w1src[i * 8];
      *(short8*)&w2c[i * 8] = *(const short8*)&w2src[i * 8];
    }
    __syncthreads();
    // GEMM1: h1 chunk = z3 @ w1c^T, +bias, GELU -> h1s bf16
#pragma unroll
    for (int nt = 0; nt < 2; ++nt) {
      int f0 = wn * 32 + nt * 16;
      floatx4 acc = {0.f, 0.f, 0.f, 0.f};
#pragma unroll
      for (int kk = 0; kk < 4; ++kk) {
        short8 bfr = *(const short8*)&w1c[(f0 + r16) * 136 + kk * 32 + quad * 8];
        acc = MFMA16(a3[kk], bfr, acc);
      }
      float bb1 = b1[fc + f0 + r16];
#pragma unroll
      for (int r = 0; r < 4; ++r) {
        float hv = acc[r] + bb1;
        float ge = 0.5f * hv * (1.f + erff(hv * 0.70710678118f));
        h1s[(strip + quad * 4 + r) * 136 + f0 + r16] = f2bf(ge);
      }
    }
    __syncthreads();
    // GEMM2 partial: zacc += h1s @ w2c^T (local K=128)
    short8 ah[4];
#pragma unroll
    for (int kk = 0; kk < 4; ++kk)
      ah[kk] = *(const short8*)&h1s[(strip + r16) * 136 + kk * 32 + quad * 8];
#pragma unroll
    for (int nt = 0; nt < 2; ++nt) {
      int o0 = wn * 32 + nt * 16;
#pragma unroll
      for (int kk = 0; kk < 4; ++kk) {
        short8 bfr = *(const short8*)&w2c[(o0 + r16) * 136 + kk * 32 + quad * 8];
        zacc[nt] = MFMA16(ah[kk], bfr, zacc[nt]);
      }
    }
  }
  __syncthreads();  // done with w1c -> outt alias safe
#pragma unroll
  for (int nt = 0; nt < 2; ++nt) {
    int o0 = wn * 32 + nt * 16;
    float bb = b2[o0 + r16];
#pragma unroll
    for (int r = 0; r < 4; ++r) {
      int px = strip + quad * 4 + r;
      outt[(o0 + r16) * 65 + px] =
          zacc[nt][r] + bb + z2[rowbase + px * 128 + o0 + r16];
    }
  }
  __syncthreads();
  for (int it = 0; it < 8; ++it) {
    int flat = it * 1024 + tid;   // o*64 + px
    int o = flat >> 6, px = flat & 63;
    out[(((size_t)(n * 128 + o)) * 64 + y) * 64 + px] = outt[o * 65 + px];
  }
}

// ----------------------------------------------------------------
extern "C" void kernel_launch(void* const* d_in, const int* in_sizes, int n_in,
                              void* d_out, int out_size, void* d_ws, size_t ws_size,
                              hipStream_t stream) {
  const float* x        = (const float*)d_in[0];
  const float* qcoeff   = (const float*)d_in[1];
  const float* wq       = (const float*)d_in[2];
  const float* bq       = (const float*)d_in[3];
  const float* wk       = (const float*)d_in[4];
  const float* bk       = (const float*)d_in[5];
  const float* wv       = (const float*)d_in[6];
  const float* bv       = (const float*)d_in[7];
  const float* rel_bias = (const float*)d_in[8];
  const float* ln1_g    = (const float*)d_in[9];
  const float* ln1_b    = (const float*)d_in[10];
  const float* bil_w    = (const float*)d_in[11];
  const float* bil_b    = (const float*)d_in[12];
  const float* ln2_g    = (const float*)d_in[13];
  const float* ln2_b    = (const float*)d_in[14];
  const float* w1       = (const float*)d_in[15];
  const float* b1       = (const float*)d_in[16];
  const float* w2       = (const float*)d_in[17];
  const float* b2       = (const float*)d_in[18];
  float* out = (float*)d_out;

  float* ws = (float*)d_ws;
  float* x_nhwc = ws;            // [N,H,W,E]
  float* xn     = ws + 1 * SZ;   // LN1 output; aliased as z0 after QKV
  float* qb     = ws + 2 * SZ;   // aliased as z2 after attention
  float* kb     = ws + 3 * SZ;   // aliased as z3 after attention
  float* vb     = ws + 4 * SZ;
  short* bf     = (short*)(ws + 5 * SZ);
  short* tb     = bf;                    // [4][128][136] bf16
  short* w1bf   = bf + 4 * 17408;        // [512][136]
  short* w2bf   = w1bf + 512 * 136;      // [4][128][136]
  short* wqbf   = w2bf + 4 * 17408;      // [128][136]
  short* wkbf   = wqbf + 17408;
  short* wvbf   = wkbf + 17408;
  float* z0 = xn;
  float* z2 = qb;
  float* z3 = kb;

  k_prep<<<64, 256, 0, stream>>>(w1, w2, wq, wk, wv, w1bf, w2bf, wqbf, wkbf, wvbf);
  k_ln1<<<256, 256, 0, stream>>>(x, ln1_g, ln1_b, x_nhwc, xn);
  k_qkv<<<256, 1024, 0, stream>>>(xn, wqbf, wkbf, wvbf, bq, bk, bv, qb, kb, vb);
  k_t<<<64, 256, 0, stream>>>(bil_w, qcoeff, tb);
  k_attn<<<1024, 256, 0, stream>>>(qb, kb, vb, rel_bias, z0);
  k_bil<<<256, 1024, 0, stream>>>(z0, tb, bil_b, x_nhwc, ln2_g, ln2_b, z2, z3);
  k_ffn<<<256, 1024, 0, stream>>>(z3, z2, w1bf, b1, w2bf, b2, out);
}